// Round 10
// baseline (1845.608 us; speedup 1.0000x reference)
//
#include <hip/hip_runtime.h>
#include <math.h>

typedef __attribute__((ext_vector_type(4))) float f32x4;
typedef __attribute__((ext_vector_type(8))) short bf16x8;

__device__ __forceinline__ unsigned short f2bf(float x) {
  union { float f; unsigned u; } v;
  v.f = x;
  unsigned r = v.u + 0x7FFF + ((v.u >> 16) & 1);
  return (unsigned short)(r >> 16);
}

__device__ __forceinline__ float sigf(float x) {
  return __builtin_amdgcn_rcpf(1.f + __expf(-x));
}
__device__ __forceinline__ float tanh_fast(float x) {
  return 2.f * __builtin_amdgcn_rcpf(1.f + __expf(-2.f * x)) - 1.f;
}

__device__ __forceinline__ float zsel(f32x4 c, int jj) {
  float ab = (jj & 1) ? c.y : c.x;
  float cd = (jj & 1) ? c.w : c.z;
  return (jj & 2) ? cd : ab;
}

__device__ __forceinline__ int clampi(int v, int lo, int hi) {
  return v < lo ? lo : (v > hi ? hi : v);
}

// ---------------------------------------------------------------------------
// Kernel A: per-token: ft gather + char conv (3,4,5) -> lstm_in[1024][450]
// ---------------------------------------------------------------------------
__global__ __launch_bounds__(64) void k_token(
    const float* __restrict__ fast_text, const float* __restrict__ char_table,
    const float* __restrict__ w3, const float* __restrict__ b3,
    const float* __restrict__ w4, const float* __restrict__ b4,
    const float* __restrict__ w5, const float* __restrict__ b5,
    const int* __restrict__ word_ids, const int* __restrict__ char_ids,
    float* __restrict__ lstm_in) {
  const int t = blockIdx.x;
  const int tid = threadIdx.x;
  __shared__ float ce[16][16];  // ce[l][ci]
  for (int i = tid; i < 256; i += 64) {
    int l = i >> 4, ci = i & 15;
    ce[l][ci] = char_table[char_ids[t * 16 + l] * 16 + ci];
  }
  __syncthreads();
  const int wid = word_ids[t];
  for (int d = tid; d < 300; d += 64)
    lstm_in[t * 450 + d] = fast_text[wid * 300 + d];
  const int f = tid;
  if (f < 50) {
    {
      float acc[14];
#pragma unroll
      for (int p = 0; p < 14; ++p) acc[p] = 0.f;
      for (int ci = 0; ci < 16; ++ci) {
#pragma unroll
        for (int kk = 0; kk < 3; ++kk) {
          float wv = w3[(f * 16 + ci) * 3 + kk];
#pragma unroll
          for (int p = 0; p < 14; ++p) acc[p] += ce[p + kk][ci] * wv;
        }
      }
      float m = acc[0];
#pragma unroll
      for (int p = 1; p < 14; ++p) m = fmaxf(m, acc[p]);
      lstm_in[t * 450 + 300 + f] = fmaxf(0.f, m + b3[f]);
    }
    {
      float acc[13];
#pragma unroll
      for (int p = 0; p < 13; ++p) acc[p] = 0.f;
      for (int ci = 0; ci < 16; ++ci) {
#pragma unroll
        for (int kk = 0; kk < 4; ++kk) {
          float wv = w4[(f * 16 + ci) * 4 + kk];
#pragma unroll
          for (int p = 0; p < 13; ++p) acc[p] += ce[p + kk][ci] * wv;
        }
      }
      float m = acc[0];
#pragma unroll
      for (int p = 1; p < 13; ++p) m = fmaxf(m, acc[p]);
      lstm_in[t * 450 + 350 + f] = fmaxf(0.f, m + b4[f]);
    }
    {
      float acc[12];
#pragma unroll
      for (int p = 0; p < 12; ++p) acc[p] = 0.f;
      for (int ci = 0; ci < 16; ++ci) {
#pragma unroll
        for (int kk = 0; kk < 5; ++kk) {
          float wv = w5[(f * 16 + ci) * 5 + kk];
#pragma unroll
          for (int p = 0; p < 12; ++p) acc[p] += ce[p + kk][ci] * wv;
        }
      }
      float m = acc[0];
#pragma unroll
      for (int p = 1; p < 12; ++p) m = fmaxf(m, acc[p]);
      lstm_in[t * 450 + 400 + f] = fmaxf(0.f, m + b5[f]);
    }
  }
}

// ---------------------------------------------------------------------------
// Generic fp32 GEMM: C[M][N] = A[M][K] @ W[N][K]^T (+ bias[N] if non-null)
// ---------------------------------------------------------------------------
__global__ __launch_bounds__(256) void gemm_nt(
    const float* __restrict__ A, const float* __restrict__ W,
    const float* __restrict__ bias, float* __restrict__ C,
    int M, int N, int K) {
  __shared__ float As[16][64];
  __shared__ float Ws[16][64];
  const int tid = threadIdx.x;
  const int tx = tid & 15, ty = tid >> 4;
  const int r0 = blockIdx.x * 64, c0 = blockIdx.y * 64;
  float acc[4][4] = {};
  for (int k0 = 0; k0 < K; k0 += 16) {
    for (int i = tid; i < 1024; i += 256) {
      int rr = i >> 4, kk = i & 15;
      int r = r0 + rr, k = k0 + kk;
      As[kk][rr] = (r < M && k < K) ? A[r * K + k] : 0.f;
      int c = c0 + rr;
      Ws[kk][rr] = (c < N && k < K) ? W[c * K + k] : 0.f;
    }
    __syncthreads();
#pragma unroll
    for (int kk = 0; kk < 16; ++kk) {
      const float4 av = *(const float4*)(&As[kk][ty * 4]);
      const float4 wv = *(const float4*)(&Ws[kk][tx * 4]);
      float a[4] = {av.x, av.y, av.z, av.w};
      float w[4] = {wv.x, wv.y, wv.z, wv.w};
#pragma unroll
      for (int i = 0; i < 4; ++i)
#pragma unroll
        for (int j = 0; j < 4; ++j) acc[i][j] += a[i] * w[j];
    }
    __syncthreads();
  }
#pragma unroll
  for (int i = 0; i < 4; ++i) {
    int r = r0 + ty * 4 + i;
    if (r >= M) continue;
#pragma unroll
    for (int j = 0; j < 4; ++j) {
      int c = c0 + tx * 4 + j;
      if (c < N) C[r * N + c] = acc[i][j] + (bias ? bias[c] : 0.f);
    }
  }
}

// ---------------------------------------------------------------------------
// Fused xproj GEMM: both directions in one launch.
// ---------------------------------------------------------------------------
__global__ __launch_bounds__(256) void gemm_xproj(
    const float* __restrict__ A,
    const float* __restrict__ Wf, const float* __restrict__ bf,
    const float* __restrict__ Wb, const float* __restrict__ bb,
    float* __restrict__ xpF, float* __restrict__ xpB) {
  const int M = 1024, N = 600, K = 450;
  const bool back = blockIdx.y >= 10;
  const float* __restrict__ W = back ? Wb : Wf;
  const float* __restrict__ bias = back ? bb : bf;
  float* __restrict__ C = back ? xpB : xpF;
  const int yb = back ? (blockIdx.y - 10) : blockIdx.y;

  __shared__ float As[16][64];
  __shared__ float Ws[16][64];
  const int tid = threadIdx.x;
  const int tx = tid & 15, ty = tid >> 4;
  const int r0 = blockIdx.x * 64, c0 = yb * 64;
  float acc[4][4] = {};
  for (int k0 = 0; k0 < K; k0 += 16) {
    for (int i = tid; i < 1024; i += 256) {
      int rr = i >> 4, kk = i & 15;
      int r = r0 + rr, k = k0 + kk;
      As[kk][rr] = (r < M && k < K) ? A[r * K + k] : 0.f;
      int c = c0 + rr;
      Ws[kk][rr] = (c < N && k < K) ? W[c * K + k] : 0.f;
    }
    __syncthreads();
#pragma unroll
    for (int kk = 0; kk < 16; ++kk) {
      const float4 av = *(const float4*)(&As[kk][ty * 4]);
      const float4 wv = *(const float4*)(&Ws[kk][tx * 4]);
      float a[4] = {av.x, av.y, av.z, av.w};
      float w[4] = {wv.x, wv.y, wv.z, wv.w};
#pragma unroll
      for (int i = 0; i < 4; ++i)
#pragma unroll
        for (int j = 0; j < 4; ++j) acc[i][j] += a[i] * w[j];
    }
    __syncthreads();
  }
#pragma unroll
  for (int i = 0; i < 4; ++i) {
    int r = r0 + ty * 4 + i;
#pragma unroll
    for (int j = 0; j < 4; ++j) {
      int c = c0 + tx * 4 + j;
      if (c < N) C[r * N + c] = acc[i][j] + bias[c];
    }
  }
}

// ---------------------------------------------------------------------------
// Kernel C: LSTM recurrence via MFMA. One block (256 thr = 4 waves) per dir.
// Weights live in AGPRs as v_mfma_f32_16x16x32_bf16 A-fragments ("a"-
// constrained inline asm) -- bypasses the 84-VGPR allocator wall that
// spilled every VALU formulation (rounds 2-9). Units padded 150->192 =
// 12 row-tiles of 16; wave w owns tiles {3w..3w+2}; per step each wave
// runs 12 chains x 5 k-tiles = 60 MFMAs, issued kt-outer so dependent
// MFMAs are 12 apart. B operand = h broadcast into all 16 columns (every
// column computes the same matvec; only the k-mapping k=(l>>4)*8+j
// matters). h is a 192-half bf16 LDS double buffer: 5 ds_read_b128 +
// 3 ds_write_b16 per wave per step. Gates: lane l owns unit
// 16T+4*(l>>4)+(l&3) -> c-state in-lane, no cross-lane exchange.
// s_nop x3 after the MFMA block guards the MFMA->v_accvgpr_read hazard
// (inline-asm MFMAs are opaque to the compiler's hazard recognizer).
// ---------------------------------------------------------------------------
__global__ __launch_bounds__(256, 1) void k_lstm(
    const float* __restrict__ xprojF, const float* __restrict__ xprojB,
    const float* __restrict__ Wh_f, const float* __restrict__ Wh_b,
    float* __restrict__ keys) {
  const int dir = blockIdx.x;
  const float* __restrict__ xp = dir ? xprojB : xprojF;
  const float* __restrict__ Wh = dir ? Wh_b : Wh_f;
  const int tid = threadIdx.x;
  const int w = tid >> 6;   // wave 0..3
  const int l = tid & 63;   // lane
  const int r16 = l & 15;   // A-fragment row within tile
  const int ch = l >> 4;    // k-chunk (A/B) and D row-group q
  const int jj = l & 3;     // owned sub-row for gate math

  __shared__ alignas(16) unsigned short hb[2][192];  // h as bf16, padded

  // ---- load A fragments: 3 tiles x 4 gates x 5 k-tiles ----
  bf16x8 A[3][4][5];
#pragma unroll
  for (int Ti = 0; Ti < 3; ++Ti) {
    const int T = w * 3 + Ti;
    const int u = T * 16 + r16;  // weight row unit
#pragma unroll
    for (int g = 0; g < 4; ++g) {
      const float* Wr = Wh + (g * 150 + (u < 150 ? u : 0)) * 150;
#pragma unroll
      for (int kt = 0; kt < 5; ++kt) {
        const int k0 = kt * 32 + ch * 8;
        float vals[8];
#pragma unroll
        for (int j2 = 0; j2 < 4; ++j2) {
          const int k = k0 + j2 * 2;  // even; 150 even => k<150 implies k+1<=149
          if (u < 150 && k < 150) {
            float2 p = *(const float2*)(Wr + k);
            vals[j2 * 2] = p.x;
            vals[j2 * 2 + 1] = p.y;
          } else {
            vals[j2 * 2] = 0.f;
            vals[j2 * 2 + 1] = 0.f;
          }
        }
        bf16x8 s;
#pragma unroll
        for (int j = 0; j < 8; ++j) s[j] = (short)f2bf(vals[j]);
        A[Ti][g][kt] = s;
      }
    }
  }

  for (int i = tid; i < 2 * 192; i += 256) hb[i / 192][i % 192] = 0;
  float cst[3] = {0.f, 0.f, 0.f};
  __syncthreads();

  int cur = 0;
  for (int step = 0; step < 1024; ++step) {
    const int t = dir ? (1023 - step) : step;

    // xp loads for this step (issued before MFMA phase; consumed after)
    float xpv[3][4];
#pragma unroll
    for (int Ti = 0; Ti < 3; ++Ti) {
      const int u = (w * 3 + Ti) * 16 + ch * 4 + jj;
      const int uc = u < 150 ? u : 149;
#pragma unroll
      for (int g = 0; g < 4; ++g) xpv[Ti][g] = xp[t * 600 + g * 150 + uc];
    }

    // zero accumulators
    f32x4 Cf[3][4];
#pragma unroll
    for (int Ti = 0; Ti < 3; ++Ti)
#pragma unroll
      for (int g = 0; g < 4; ++g) Cf[Ti][g] = (f32x4){0.f, 0.f, 0.f, 0.f};

    // MFMA phase: kt outer, 12 interleaved chains
#pragma unroll
    for (int kt = 0; kt < 5; ++kt) {
      union { float4 f; bf16x8 s; } cv;
      cv.f = *(const float4*)((const char*)&hb[cur][0] + kt * 64 + ch * 16);
      const bf16x8 b = cv.s;
#pragma unroll
      for (int Ti = 0; Ti < 3; ++Ti)
#pragma unroll
        for (int g = 0; g < 4; ++g)
          asm volatile("v_mfma_f32_16x16x32_bf16 %0, %1, %2, %0"
                       : "+a"(Cf[Ti][g])
                       : "a"(A[Ti][g][kt]), "v"(b));
    }
    asm volatile("s_nop 7\n\ts_nop 7\n\ts_nop 7");

    // gate phase: lane owns unit 16T + 4*ch + jj
#pragma unroll
    for (int Ti = 0; Ti < 3; ++Ti) {
      const int u = (w * 3 + Ti) * 16 + ch * 4 + jj;
      const float zi = zsel(Cf[Ti][0], jj) + xpv[Ti][0];
      const float zf = zsel(Cf[Ti][1], jj) + xpv[Ti][1];
      const float zg = zsel(Cf[Ti][2], jj) + xpv[Ti][2];
      const float zo = zsel(Cf[Ti][3], jj) + xpv[Ti][3];
      const float ig = sigf(zi);
      const float fg = sigf(zf);
      const float gg = tanh_fast(zg);
      const float og = sigf(zo);
      cst[Ti] = fg * cst[Ti] + ig * gg;
      const float h = og * tanh_fast(cst[Ti]);
      if ((l & 12) == 0 && u < 150) {
        hb[cur ^ 1][u] = f2bf(h);
        keys[t * 300 + dir * 150 + u] = h;
      }
    }
    cur ^= 1;
    __syncthreads();
  }
}

// ---------------------------------------------------------------------------
// Kernel D: span scorer -> enc[512][1000]
// ---------------------------------------------------------------------------
__global__ __launch_bounds__(320) void k_span(
    const float* __restrict__ keys, const float* __restrict__ lstm_in,
    const float* __restrict__ W1, const float* __restrict__ b1,
    const float* __restrict__ W2, const float* __restrict__ b2,
    const float* __restrict__ w_out, const float* __restrict__ feat_table,
    const int* __restrict__ espans, float* __restrict__ enc) {
  const int e = blockIdx.x;
  const int tid = threadIdx.x;
  const int s = espans[e * 4 + 0];
  const int en = espans[e * 4 + 1];
  const int f0 = espans[e * 4 + 2];
  const int f1 = espans[e * 4 + 3];

  __shared__ float ksh[10][300];
  __shared__ float hsh[10][152];
  __shared__ float h2sh[10][152];
  __shared__ float att[10];
  __shared__ float scl[2];

  for (int i = tid; i < 3000; i += 320) {
    int p = i / 300, d = i % 300;
    int row = clampi(s + p, 0, 1023);
    ksh[p][d] = keys[row * 300 + d];
  }
  __syncthreads();

  if (tid < 152) {
    int jjj = tid;
    if (jjj < 150) {
      float acc[10];
#pragma unroll
      for (int p = 0; p < 10; ++p) acc[p] = b1[jjj];
      for (int k = 0; k < 300; k += 4) {
        float w0 = W1[(k + 0) * 150 + jjj];
        float w1 = W1[(k + 1) * 150 + jjj];
        float w2 = W1[(k + 2) * 150 + jjj];
        float w3 = W1[(k + 3) * 150 + jjj];
#pragma unroll
        for (int p = 0; p < 10; ++p) {
          const float4 kv = *(const float4*)(&ksh[p][k]);
          acc[p] += kv.x * w0 + kv.y * w1 + kv.z * w2 + kv.w * w3;
        }
      }
#pragma unroll
      for (int p = 0; p < 10; ++p) hsh[p][jjj] = fmaxf(acc[p], 0.f);
    } else {
#pragma unroll
      for (int p = 0; p < 10; ++p) hsh[p][jjj] = 0.f;
    }
  }
  __syncthreads();

  if (tid < 150) {
    int jjj = tid;
    float acc[10];
#pragma unroll
    for (int p = 0; p < 10; ++p) acc[p] = b2[jjj];
    for (int k = 0; k < 152; k += 4) {
      float w0 = (k + 0 < 150) ? W2[(k + 0) * 150 + jjj] : 0.f;
      float w1 = (k + 1 < 150) ? W2[(k + 1) * 150 + jjj] : 0.f;
      float w2 = (k + 2 < 150) ? W2[(k + 2) * 150 + jjj] : 0.f;
      float w3 = (k + 3 < 150) ? W2[(k + 3) * 150 + jjj] : 0.f;
#pragma unroll
      for (int p = 0; p < 10; ++p) {
        const float4 hv = *(const float4*)(&hsh[p][k]);
        acc[p] += hv.x * w0 + hv.y * w1 + hv.z * w2 + hv.w * w3;
      }
    }
#pragma unroll
    for (int p = 0; p < 10; ++p) h2sh[p][jjj] = fmaxf(acc[p], 0.f);
  }
  __syncthreads();

  if (tid < 10) {
    float lg = -1e30f;
    if (tid < en - s) {
      float d = 0.f;
      for (int k = 0; k < 150; ++k) d += h2sh[tid][k] * w_out[k];
      lg = d;
    }
    att[tid] = lg;
  }
  if (tid >= 64 && tid < 66) {
    int r = tid - 64;
    int fi = (r == 0) ? f0 : f1;
    float nsq = 0.f;
    for (int k = 0; k < 50; ++k) {
      float v = feat_table[fi * 50 + k];
      nsq += v * v;
    }
    float n = sqrtf(nsq);
    scl[r] = fminf(1.f, 1.f / fmaxf(n, 1e-7f));
  }
  __syncthreads();

  if (tid == 0) {
    float m = -1e30f;
    for (int p = 0; p < 10; ++p) m = fmaxf(m, att[p]);
    float ex[10];
    float ssum = 0.f;
    for (int p = 0; p < 10; ++p) {
      ex[p] = expf(att[p] - m);
      ssum += ex[p];
    }
    for (int p = 0; p < 10; ++p) att[p] = ex[p] / ssum;
  }
  __syncthreads();

  if (tid < 300) {
    int d = tid;
    float xf = keys[s * 300 + d];
    float xl = keys[(en - 1) * 300 + d];
    float xh = 0.f;
#pragma unroll
    for (int p = 0; p < 10; ++p) {
      int row = clampi(s + p, 0, 1023);
      xh += att[p] * lstm_in[row * 450 + d];
    }
    enc[e * 1000 + d] = xf;
    enc[e * 1000 + 300 + d] = xl;
    enc[e * 1000 + 600 + d] = xh;
  }
  if (tid < 100) {
    int r = tid / 50, cc = tid % 50;
    int fi = (r == 0) ? f0 : f1;
    enc[e * 1000 + 900 + tid] = feat_table[fi * 50 + cc] * scl[r];
  }
}

// ---------------------------------------------------------------------------
// Kernel E: small = enc @ affine_W + affine_b   (4 spans per block)
// ---------------------------------------------------------------------------
__global__ __launch_bounds__(320) void k_affine(
    const float* __restrict__ enc, const float* __restrict__ W,
    const float* __restrict__ bias, float* __restrict__ small) {
  const int e0 = blockIdx.x * 4;
  const int tid = threadIdx.x;
  __shared__ float es[4][1000];
  for (int i = tid; i < 4000; i += 320) es[i / 1000][i % 1000] = enc[e0 * 1000 + i];
  __syncthreads();
  if (tid < 300) {
    float a0 = bias[tid], a1 = bias[tid], a2 = bias[tid], a3 = bias[tid];
    for (int k = 0; k < 1000; k += 4) {
      float w0 = W[(k + 0) * 300 + tid];
      float w1 = W[(k + 1) * 300 + tid];
      float w2 = W[(k + 2) * 300 + tid];
      float w3 = W[(k + 3) * 300 + tid];
      const float4 v0 = *(const float4*)(&es[0][k]);
      const float4 v1 = *(const float4*)(&es[1][k]);
      const float4 v2 = *(const float4*)(&es[2][k]);
      const float4 v3 = *(const float4*)(&es[3][k]);
      a0 += v0.x * w0 + v0.y * w1 + v0.z * w2 + v0.w * w3;
      a1 += v1.x * w0 + v1.y * w1 + v1.z * w2 + v1.w * w3;
      a2 += v2.x * w0 + v2.y * w1 + v2.z * w2 + v2.w * w3;
      a3 += v3.x * w0 + v3.y * w1 + v3.z * w2 + v3.w * w3;
    }
    small[(e0 + 0) * 300 + tid] = a0;
    small[(e0 + 1) * 300 + tid] = a1;
    small[(e0 + 2) * 300 + tid] = a2;
    small[(e0 + 3) * 300 + tid] = a3;
  }
}

// ---------------------------------------------------------------------------
__global__ __launch_bounds__(64) void k_renorm(
    const float* __restrict__ actors, float* __restrict__ actorsN) {
  const int a = blockIdx.x;
  const int l = threadIdx.x;
  float nsq = 0.f;
  for (int d = l; d < 300; d += 64) {
    float v = actors[a * 300 + d];
    nsq += v * v;
  }
  for (int off = 32; off; off >>= 1) nsq += __shfl_down(nsq, off);
  nsq = __shfl(nsq, 0);
  float sc = fminf(1.f, 1.f / fmaxf(sqrtf(nsq), 1e-7f));
  for (int d = l; d < 300; d += 64) actorsN[a * 300 + d] = actors[a * 300 + d] * sc;
}

// ---------------------------------------------------------------------------
__global__ __launch_bounds__(64) void k_lse(
    const float* __restrict__ link, float* __restrict__ out) {
  const int a = blockIdx.x;
  const int l = threadIdx.x;
  float v[8];
  float m = -1e30f;
#pragma unroll
  for (int i = 0; i < 8; ++i) {
    v[i] = link[a * 512 + l + i * 64];
    m = fmaxf(m, v[i]);
  }
  for (int off = 32; off; off >>= 1) m = fmaxf(m, __shfl_xor(m, off));
  float ssum = 0.f;
#pragma unroll
  for (int i = 0; i < 8; ++i) ssum += expf(v[i] - m);
  for (int off = 32; off; off >>= 1) ssum += __shfl_xor(ssum, off);
  if (l == 0) out[a] = logf(ssum) + m;
}

// ---------------------------------------------------------------------------
extern "C" void kernel_launch(void* const* d_in, const int* in_sizes, int n_in,
                              void* d_out, int out_size, void* d_ws, size_t ws_size,
                              hipStream_t stream) {
  const float* fast_text = (const float*)d_in[0];
  const float* actor_matrix = (const float*)d_in[1];
  const float* char_table = (const float*)d_in[2];
  const float* w3 = (const float*)d_in[3];
  const float* b3 = (const float*)d_in[4];
  const float* w4 = (const float*)d_in[5];
  const float* b4 = (const float*)d_in[6];
  const float* w5 = (const float*)d_in[7];
  const float* b5 = (const float*)d_in[8];
  const float* Wi_f = (const float*)d_in[9];
  const float* Wh_f = (const float*)d_in[10];
  const float* b_f = (const float*)d_in[11];
  const float* Wi_b = (const float*)d_in[12];
  const float* Wh_b = (const float*)d_in[13];
  const float* b_b = (const float*)d_in[14];
  const float* alpha_W1 = (const float*)d_in[15];
  const float* alpha_b1 = (const float*)d_in[16];
  const float* alpha_W2 = (const float*)d_in[17];
  const float* alpha_b2 = (const float*)d_in[18];
  const float* alpha_w_out = (const float*)d_in[19];
  const float* feat_table = (const float*)d_in[20];
  const float* affine_W = (const float*)d_in[21];
  const float* affine_b = (const float*)d_in[22];
  const int* word_ids = (const int*)d_in[23];
  const int* char_ids = (const int*)d_in[24];
  const int* espans = (const int*)d_in[25];

  float* ws = (float*)d_ws;
  float* lstm_in = ws;                 // 1024*450
  float* xpF = lstm_in + 460800;       // 1024*600
  float* xpB = xpF + 614400;           // 1024*600
  float* keys = xpB + 614400;          // 1024*300
  float* enc = keys + 307200;          // 512*1000
  float* small = enc + 512000;         // 512*300
  float* actN = small + 153600;        // 2000*300

  float* out = (float*)d_out;
  float* score_link = out + 2000;  // 2000 x 512

  k_token<<<1024, 64, 0, stream>>>(fast_text, char_table, w3, b3, w4, b4, w5, b5,
                                   word_ids, char_ids, lstm_in);
  gemm_xproj<<<dim3(16, 20), 256, 0, stream>>>(lstm_in, Wi_f, b_f, Wi_b, b_b,
                                               xpF, xpB);
  k_lstm<<<2, 256, 0, stream>>>(xpF, xpB, Wh_f, Wh_b, keys);
  k_renorm<<<2000, 64, 0, stream>>>(actor_matrix, actN);
  k_span<<<512, 320, 0, stream>>>(keys, lstm_in, alpha_W1, alpha_b1, alpha_W2,
                                  alpha_b2, alpha_w_out, feat_table, espans, enc);
  k_affine<<<128, 320, 0, stream>>>(enc, affine_W, affine_b, small);
  gemm_nt<<<dim3(32, 8), 256, 0, stream>>>(actN, small, nullptr, score_link,
                                           2000, 512, 300);
  k_lse<<<2000, 64, 0, stream>>>(score_link, out);
}

// Round 11
// 1287.121 us; speedup vs baseline: 1.4339x; 1.4339x over previous
//
#include <hip/hip_runtime.h>
#include <math.h>

typedef _Float16 h2f __attribute__((ext_vector_type(2)));

__device__ __forceinline__ float fdot2f(h2f a, h2f b, float c) {
#if __has_builtin(__builtin_amdgcn_fdot2)
  return __builtin_amdgcn_fdot2(a, b, c, false);
#else
  return c + (float)a[0] * (float)b[0] + (float)a[1] * (float)b[1];
#endif
}

__device__ __forceinline__ h2f bits_h2f(int b) {
  union { int i; h2f h; } u;
  u.i = b;
  return u.h;
}
__device__ __forceinline__ int h2f_bits(h2f h) {
  union { h2f h; int i; } u;
  u.h = h;
  return u.i;
}

// DPP quad_perm cross-lane (VALU pipe): 0xB1 -> lane^1, 0x4E -> lane^2.
template <int CTRL>
__device__ __forceinline__ float dpp_f(float x) {
  union { float f; int i; } u, r;
  u.f = x;
  r.i = __builtin_amdgcn_update_dpp(0, u.i, CTRL, 0xF, 0xF, false);
  return r.f;
}

__device__ __forceinline__ float sigf(float x) {
  return __builtin_amdgcn_rcpf(1.f + __expf(-x));
}
__device__ __forceinline__ float tanh_fast(float x) {
  return 2.f * __builtin_amdgcn_rcpf(1.f + __expf(-2.f * x)) - 1.f;
}

__device__ __forceinline__ int clampi(int v, int lo, int hi) {
  return v < lo ? lo : (v > hi ? hi : v);
}

// ---------------------------------------------------------------------------
// Kernel A: per-token: ft gather + char conv (3,4,5) -> lstm_in[1024][450]
// ---------------------------------------------------------------------------
__global__ __launch_bounds__(64) void k_token(
    const float* __restrict__ fast_text, const float* __restrict__ char_table,
    const float* __restrict__ w3, const float* __restrict__ b3,
    const float* __restrict__ w4, const float* __restrict__ b4,
    const float* __restrict__ w5, const float* __restrict__ b5,
    const int* __restrict__ word_ids, const int* __restrict__ char_ids,
    float* __restrict__ lstm_in) {
  const int t = blockIdx.x;
  const int tid = threadIdx.x;
  __shared__ float ce[16][16];  // ce[l][ci]
  for (int i = tid; i < 256; i += 64) {
    int l = i >> 4, ci = i & 15;
    ce[l][ci] = char_table[char_ids[t * 16 + l] * 16 + ci];
  }
  __syncthreads();
  const int wid = word_ids[t];
  for (int d = tid; d < 300; d += 64)
    lstm_in[t * 450 + d] = fast_text[wid * 300 + d];
  const int f = tid;
  if (f < 50) {
    {
      float acc[14];
#pragma unroll
      for (int p = 0; p < 14; ++p) acc[p] = 0.f;
      for (int ci = 0; ci < 16; ++ci) {
#pragma unroll
        for (int kk = 0; kk < 3; ++kk) {
          float wv = w3[(f * 16 + ci) * 3 + kk];
#pragma unroll
          for (int p = 0; p < 14; ++p) acc[p] += ce[p + kk][ci] * wv;
        }
      }
      float m = acc[0];
#pragma unroll
      for (int p = 1; p < 14; ++p) m = fmaxf(m, acc[p]);
      lstm_in[t * 450 + 300 + f] = fmaxf(0.f, m + b3[f]);
    }
    {
      float acc[13];
#pragma unroll
      for (int p = 0; p < 13; ++p) acc[p] = 0.f;
      for (int ci = 0; ci < 16; ++ci) {
#pragma unroll
        for (int kk = 0; kk < 4; ++kk) {
          float wv = w4[(f * 16 + ci) * 4 + kk];
#pragma unroll
          for (int p = 0; p < 13; ++p) acc[p] += ce[p + kk][ci] * wv;
        }
      }
      float m = acc[0];
#pragma unroll
      for (int p = 1; p < 13; ++p) m = fmaxf(m, acc[p]);
      lstm_in[t * 450 + 350 + f] = fmaxf(0.f, m + b4[f]);
    }
    {
      float acc[12];
#pragma unroll
      for (int p = 0; p < 12; ++p) acc[p] = 0.f;
      for (int ci = 0; ci < 16; ++ci) {
#pragma unroll
        for (int kk = 0; kk < 5; ++kk) {
          float wv = w5[(f * 16 + ci) * 5 + kk];
#pragma unroll
          for (int p = 0; p < 12; ++p) acc[p] += ce[p + kk][ci] * wv;
        }
      }
      float m = acc[0];
#pragma unroll
      for (int p = 1; p < 12; ++p) m = fmaxf(m, acc[p]);
      lstm_in[t * 450 + 400 + f] = fmaxf(0.f, m + b5[f]);
    }
  }
}

// ---------------------------------------------------------------------------
// Generic fp32 GEMM: C[M][N] = A[M][K] @ W[N][K]^T (+ bias[N] if non-null)
// ---------------------------------------------------------------------------
__global__ __launch_bounds__(256) void gemm_nt(
    const float* __restrict__ A, const float* __restrict__ W,
    const float* __restrict__ bias, float* __restrict__ C,
    int M, int N, int K) {
  __shared__ float As[16][64];
  __shared__ float Ws[16][64];
  const int tid = threadIdx.x;
  const int tx = tid & 15, ty = tid >> 4;
  const int r0 = blockIdx.x * 64, c0 = blockIdx.y * 64;
  float acc[4][4] = {};
  for (int k0 = 0; k0 < K; k0 += 16) {
    for (int i = tid; i < 1024; i += 256) {
      int rr = i >> 4, kk = i & 15;
      int r = r0 + rr, k = k0 + kk;
      As[kk][rr] = (r < M && k < K) ? A[r * K + k] : 0.f;
      int c = c0 + rr;
      Ws[kk][rr] = (c < N && k < K) ? W[c * K + k] : 0.f;
    }
    __syncthreads();
#pragma unroll
    for (int kk = 0; kk < 16; ++kk) {
      const float4 av = *(const float4*)(&As[kk][ty * 4]);
      const float4 wv = *(const float4*)(&Ws[kk][tx * 4]);
      float a[4] = {av.x, av.y, av.z, av.w};
      float w[4] = {wv.x, wv.y, wv.z, wv.w};
#pragma unroll
      for (int i = 0; i < 4; ++i)
#pragma unroll
        for (int j = 0; j < 4; ++j) acc[i][j] += a[i] * w[j];
    }
    __syncthreads();
  }
#pragma unroll
  for (int i = 0; i < 4; ++i) {
    int r = r0 + ty * 4 + i;
    if (r >= M) continue;
#pragma unroll
    for (int j = 0; j < 4; ++j) {
      int c = c0 + tx * 4 + j;
      if (c < N) C[r * N + c] = acc[i][j] + (bias ? bias[c] : 0.f);
    }
  }
}

// ---------------------------------------------------------------------------
// Fused xproj GEMM: both directions in one launch.
// ---------------------------------------------------------------------------
__global__ __launch_bounds__(256) void gemm_xproj(
    const float* __restrict__ A,
    const float* __restrict__ Wf, const float* __restrict__ bf,
    const float* __restrict__ Wb, const float* __restrict__ bb,
    float* __restrict__ xpF, float* __restrict__ xpB) {
  const int M = 1024, N = 600, K = 450;
  const bool back = blockIdx.y >= 10;
  const float* __restrict__ W = back ? Wb : Wf;
  const float* __restrict__ bias = back ? bb : bf;
  float* __restrict__ C = back ? xpB : xpF;
  const int yb = back ? (blockIdx.y - 10) : blockIdx.y;

  __shared__ float As[16][64];
  __shared__ float Ws[16][64];
  const int tid = threadIdx.x;
  const int tx = tid & 15, ty = tid >> 4;
  const int r0 = blockIdx.x * 64, c0 = yb * 64;
  float acc[4][4] = {};
  for (int k0 = 0; k0 < K; k0 += 16) {
    for (int i = tid; i < 1024; i += 256) {
      int rr = i >> 4, kk = i & 15;
      int r = r0 + rr, k = k0 + kk;
      As[kk][rr] = (r < M && k < K) ? A[r * K + k] : 0.f;
      int c = c0 + rr;
      Ws[kk][rr] = (c < N && k < K) ? W[c * K + k] : 0.f;
    }
    __syncthreads();
#pragma unroll
    for (int kk = 0; kk < 16; ++kk) {
      const float4 av = *(const float4*)(&As[kk][ty * 4]);
      const float4 wv = *(const float4*)(&Ws[kk][tx * 4]);
      float a[4] = {av.x, av.y, av.z, av.w};
      float w[4] = {wv.x, wv.y, wv.z, wv.w};
#pragma unroll
      for (int i = 0; i < 4; ++i)
#pragma unroll
        for (int j = 0; j < 4; ++j) acc[i][j] += a[i] * w[j];
    }
    __syncthreads();
  }
#pragma unroll
  for (int i = 0; i < 4; ++i) {
    int r = r0 + ty * 4 + i;
#pragma unroll
    for (int j = 0; j < 4; ++j) {
      int c = c0 + tx * 4 + j;
      if (c < N) C[r * N + c] = acc[i][j] + bias[c];
    }
  }
}

// ---------------------------------------------------------------------------
// Kernel C: LSTM recurrence, one block per direction. Split-K4 (r8 body):
// thread (u = tid>>2, g = tid&3) computes partials of all 4 gate rows of
// unit u over k-quarter g (5 ds_read_b128/thread/step). 2-stage DPP quad
// reduce completes the sums; thread g ends owning row g*150+u.
// Register fix (r10 lesson): attributes never move the 84-VGPR heuristic,
// but inline-asm "a"-constrained operands FORCE allocation (r10: 240 AGPR
// fragments resident, no scratch signature). So w0,w1 stay plain VGPR
// arrays (fit the 84 budget with staging) and w2,w3 are pinned in AGPRs
// via v_accvgpr_write at init + v_accvgpr_read (pure, schedulable) in the
// loop. Per-wave footprint ~84 arch + 40 acc = 124; 3 waves/SIMD * 128
// = 384 <= 512 capacity.
// ---------------------------------------------------------------------------
__global__ __launch_bounds__(640, 1) void k_lstm(
    const float* __restrict__ xprojF, const float* __restrict__ xprojB,
    const float* __restrict__ Wh_f, const float* __restrict__ Wh_b,
    float* __restrict__ keys) {
  const int dir = blockIdx.x;
  const float* __restrict__ xp = dir ? xprojB : xprojF;
  const float* __restrict__ Wh = dir ? Wh_b : Wh_f;
  const int tid = threadIdx.x;
  const int u = tid >> 2;                  // hidden unit (active < 150)
  const int g = tid & 3;                   // k-quarter / final gate row
  const int uu = u < 150 ? u : 149;        // clamped for safe addressing
  const int row = g * 150 + uu;
  const bool act = (tid < 600);

  __shared__ alignas(16) h2f hbuf[2][80];  // h packed f16: 150 + 10 zero pad

  // weights: 4 gate rows x 20 h2f covering halfs [40g, 40g+40)
  h2f w0[20], w1[20];     // gates 0,1: plain VGPR arrays
  int wa2[20], wa3[20];   // gates 2,3: AGPR-pinned via inline asm
  {
    const float* R0 = Wh + (0 * 150 + uu) * 150;
    const float* R1 = Wh + (1 * 150 + uu) * 150;
    const float* R2 = Wh + (2 * 150 + uu) * 150;
    const float* R3 = Wh + (3 * 150 + uu) * 150;
#pragma unroll
    for (int kk = 0; kk < 20; ++kk) {
      const int k = 40 * g + 2 * kk;
      float a0 = 0.f, a1 = 0.f, b0 = 0.f, b1 = 0.f;
      float c0 = 0.f, c1 = 0.f, d0 = 0.f, d1 = 0.f;
      if (k < 150) {  // k even -> k+1 <= 149 also valid
        float2 p;
        p = *(const float2*)(R0 + k); a0 = p.x; a1 = p.y;
        p = *(const float2*)(R1 + k); b0 = p.x; b1 = p.y;
        p = *(const float2*)(R2 + k); c0 = p.x; c1 = p.y;
        p = *(const float2*)(R3 + k); d0 = p.x; d1 = p.y;
      }
      h2f v;
      v[0] = (_Float16)a0; v[1] = (_Float16)a1; w0[kk] = v;
      v[0] = (_Float16)b0; v[1] = (_Float16)b1; w1[kk] = v;
      h2f v2, v3;
      v2[0] = (_Float16)c0; v2[1] = (_Float16)c1;
      v3[0] = (_Float16)d0; v3[1] = (_Float16)d1;
      asm("v_accvgpr_write_b32 %0, %1" : "=a"(wa2[kk]) : "v"(h2f_bits(v2)));
      asm("v_accvgpr_write_b32 %0, %1" : "=a"(wa3[kk]) : "v"(h2f_bits(v3)));
    }
  }
  for (int i = tid; i < 160; i += 640) {
    h2f z;
    z[0] = (_Float16)0.f;
    z[1] = (_Float16)0.f;
    hbuf[i / 80][i % 80] = z;
  }
  float c = 0.f;
  float xv = xp[(dir ? 1023 : 0) * 600 + row];
  __syncthreads();

  int cur = 0;
  for (int step = 0; step < 1024; ++step) {
    const int t = dir ? (1023 - step) : step;
    const int tn = dir ? (t > 0 ? t - 1 : 0) : (t < 1023 ? t + 1 : 1023);
    // prefetch next step's xp (hidden under the dot chain)
    const float xv_next = xp[tn * 600 + row];
    // 5 ds_read_b128 of this thread's k-quarter (4 broadcast groups/wave)
    const float4* hv = (const float4*)hbuf[cur] + 5 * g;
    float a0 = 0.f, a1 = 0.f, a2 = 0.f, a3 = 0.f;
#pragma unroll
    for (int i = 0; i < 5; ++i) {
      float4 q = hv[i];
      const h2f* hh = (const h2f*)&q;
#pragma unroll
      for (int m = 0; m < 4; ++m) {
        a0 = fdot2f(w0[4 * i + m], hh[m], a0);
        a1 = fdot2f(w1[4 * i + m], hh[m], a1);
        int t2, t3;
        asm("v_accvgpr_read_b32 %0, %1" : "=v"(t2) : "a"(wa2[4 * i + m]));
        asm("v_accvgpr_read_b32 %0, %1" : "=v"(t3) : "a"(wa3[4 * i + m]));
        a2 = fdot2f(bits_h2f(t2), hh[m], a2);
        a3 = fdot2f(bits_h2f(t3), hh[m], a3);
      }
    }
    // stage 1: sum quarters {g, g^1} for each row
    const float e0 = a0 + dpp_f<0xB1>(a0);
    const float e1 = a1 + dpp_f<0xB1>(a1);
    const float e2 = a2 + dpp_f<0xB1>(a2);
    const float e3 = a3 + dpp_f<0xB1>(a3);
    const float fa = (g & 1) ? e1 : e0;
    const float fb = (g & 1) ? e3 : e2;
    // stage 2: sum quarters {g^2, g^3}
    const float ga_ = fa + dpp_f<0x4E>(fa);
    const float gb_ = fb + dpp_f<0x4E>(fb);
    const float z = ((g & 2) ? gb_ : ga_) + xv;
    xv = xv_next;
    // nonlinearity: sigmoid for i,f,o; tanh for g
    const float zz = (g == 2) ? 2.f * z : z;
    const float s = sigf(zz);
    const float val = (g == 2) ? (2.f * s - 1.f) : s;
    // gate exchange within the quad (DPP)
    const float v1 = dpp_f<0xB1>(val);  // at g0: f
    const float gv = dpp_f<0x4E>(val);  // at g0: g
    const float ov = dpp_f<0x4E>(v1);   // at g0: o
    if (act && g == 0) {
      c = v1 * c + val * gv;
      const float h = ov * tanh_fast(c);
      keys[t * 300 + dir * 150 + u] = h;
      ((_Float16*)hbuf[cur ^ 1])[u] = (_Float16)h;
    }
    cur ^= 1;
    __syncthreads();
  }
}

// ---------------------------------------------------------------------------
// Kernel D: span scorer -> enc[512][1000]
// ---------------------------------------------------------------------------
__global__ __launch_bounds__(320) void k_span(
    const float* __restrict__ keys, const float* __restrict__ lstm_in,
    const float* __restrict__ W1, const float* __restrict__ b1,
    const float* __restrict__ W2, const float* __restrict__ b2,
    const float* __restrict__ w_out, const float* __restrict__ feat_table,
    const int* __restrict__ espans, float* __restrict__ enc) {
  const int e = blockIdx.x;
  const int tid = threadIdx.x;
  const int s = espans[e * 4 + 0];
  const int en = espans[e * 4 + 1];
  const int f0 = espans[e * 4 + 2];
  const int f1 = espans[e * 4 + 3];

  __shared__ float ksh[10][300];
  __shared__ float hsh[10][152];
  __shared__ float h2sh[10][152];
  __shared__ float att[10];
  __shared__ float scl[2];

  for (int i = tid; i < 3000; i += 320) {
    int p = i / 300, d = i % 300;
    int row = clampi(s + p, 0, 1023);
    ksh[p][d] = keys[row * 300 + d];
  }
  __syncthreads();

  if (tid < 152) {
    int jj = tid;
    if (jj < 150) {
      float acc[10];
#pragma unroll
      for (int p = 0; p < 10; ++p) acc[p] = b1[jj];
      for (int k = 0; k < 300; k += 4) {
        float w0 = W1[(k + 0) * 150 + jj];
        float w1 = W1[(k + 1) * 150 + jj];
        float w2 = W1[(k + 2) * 150 + jj];
        float w3 = W1[(k + 3) * 150 + jj];
#pragma unroll
        for (int p = 0; p < 10; ++p) {
          const float4 kv = *(const float4*)(&ksh[p][k]);
          acc[p] += kv.x * w0 + kv.y * w1 + kv.z * w2 + kv.w * w3;
        }
      }
#pragma unroll
      for (int p = 0; p < 10; ++p) hsh[p][jj] = fmaxf(acc[p], 0.f);
    } else {
#pragma unroll
      for (int p = 0; p < 10; ++p) hsh[p][jj] = 0.f;
    }
  }
  __syncthreads();

  if (tid < 150) {
    int jj = tid;
    float acc[10];
#pragma unroll
    for (int p = 0; p < 10; ++p) acc[p] = b2[jj];
    for (int k = 0; k < 152; k += 4) {
      float w0 = (k + 0 < 150) ? W2[(k + 0) * 150 + jj] : 0.f;
      float w1 = (k + 1 < 150) ? W2[(k + 1) * 150 + jj] : 0.f;
      float w2 = (k + 2 < 150) ? W2[(k + 2) * 150 + jj] : 0.f;
      float w3 = (k + 3 < 150) ? W2[(k + 3) * 150 + jj] : 0.f;
#pragma unroll
      for (int p = 0; p < 10; ++p) {
        const float4 hv = *(const float4*)(&hsh[p][k]);
        acc[p] += hv.x * w0 + hv.y * w1 + hv.z * w2 + hv.w * w3;
      }
    }
#pragma unroll
    for (int p = 0; p < 10; ++p) h2sh[p][jj] = fmaxf(acc[p], 0.f);
  }
  __syncthreads();

  if (tid < 10) {
    float lg = -1e30f;
    if (tid < en - s) {
      float d = 0.f;
      for (int k = 0; k < 150; ++k) d += h2sh[tid][k] * w_out[k];
      lg = d;
    }
    att[tid] = lg;
  }
  if (tid >= 64 && tid < 66) {
    int r = tid - 64;
    int fi = (r == 0) ? f0 : f1;
    float nsq = 0.f;
    for (int k = 0; k < 50; ++k) {
      float v = feat_table[fi * 50 + k];
      nsq += v * v;
    }
    float n = sqrtf(nsq);
    scl[r] = fminf(1.f, 1.f / fmaxf(n, 1e-7f));
  }
  __syncthreads();

  if (tid == 0) {
    float m = -1e30f;
    for (int p = 0; p < 10; ++p) m = fmaxf(m, att[p]);
    float ex[10];
    float ssum = 0.f;
    for (int p = 0; p < 10; ++p) {
      ex[p] = expf(att[p] - m);
      ssum += ex[p];
    }
    for (int p = 0; p < 10; ++p) att[p] = ex[p] / ssum;
  }
  __syncthreads();

  if (tid < 300) {
    int d = tid;
    float xf = keys[s * 300 + d];
    float xl = keys[(en - 1) * 300 + d];
    float xh = 0.f;
#pragma unroll
    for (int p = 0; p < 10; ++p) {
      int row = clampi(s + p, 0, 1023);
      xh += att[p] * lstm_in[row * 450 + d];
    }
    enc[e * 1000 + d] = xf;
    enc[e * 1000 + 300 + d] = xl;
    enc[e * 1000 + 600 + d] = xh;
  }
  if (tid < 100) {
    int r = tid / 50, cc = tid % 50;
    int fi = (r == 0) ? f0 : f1;
    enc[e * 1000 + 900 + tid] = feat_table[fi * 50 + cc] * scl[r];
  }
}

// ---------------------------------------------------------------------------
// Kernel E: small = enc @ affine_W + affine_b   (4 spans per block)
// ---------------------------------------------------------------------------
__global__ __launch_bounds__(320) void k_affine(
    const float* __restrict__ enc, const float* __restrict__ W,
    const float* __restrict__ bias, float* __restrict__ small) {
  const int e0 = blockIdx.x * 4;
  const int tid = threadIdx.x;
  __shared__ float es[4][1000];
  for (int i = tid; i < 4000; i += 320) es[i / 1000][i % 1000] = enc[e0 * 1000 + i];
  __syncthreads();
  if (tid < 300) {
    float a0 = bias[tid], a1 = bias[tid], a2 = bias[tid], a3 = bias[tid];
    for (int k = 0; k < 1000; k += 4) {
      float w0 = W[(k + 0) * 300 + tid];
      float w1 = W[(k + 1) * 300 + tid];
      float w2 = W[(k + 2) * 300 + tid];
      float w3 = W[(k + 3) * 300 + tid];
      const float4 v0 = *(const float4*)(&es[0][k]);
      const float4 v1 = *(const float4*)(&es[1][k]);
      const float4 v2 = *(const float4*)(&es[2][k]);
      const float4 v3 = *(const float4*)(&es[3][k]);
      a0 += v0.x * w0 + v0.y * w1 + v0.z * w2 + v0.w * w3;
      a1 += v1.x * w0 + v1.y * w1 + v1.z * w2 + v1.w * w3;
      a2 += v2.x * w0 + v2.y * w1 + v2.z * w2 + v2.w * w3;
      a3 += v3.x * w0 + v3.y * w1 + v3.z * w2 + v3.w * w3;
    }
    small[(e0 + 0) * 300 + tid] = a0;
    small[(e0 + 1) * 300 + tid] = a1;
    small[(e0 + 2) * 300 + tid] = a2;
    small[(e0 + 3) * 300 + tid] = a3;
  }
}

// ---------------------------------------------------------------------------
__global__ __launch_bounds__(64) void k_renorm(
    const float* __restrict__ actors, float* __restrict__ actorsN) {
  const int a = blockIdx.x;
  const int l = threadIdx.x;
  float nsq = 0.f;
  for (int d = l; d < 300; d += 64) {
    float v = actors[a * 300 + d];
    nsq += v * v;
  }
  for (int off = 32; off; off >>= 1) nsq += __shfl_down(nsq, off);
  nsq = __shfl(nsq, 0);
  float sc = fminf(1.f, 1.f / fmaxf(sqrtf(nsq), 1e-7f));
  for (int d = l; d < 300; d += 64) actorsN[a * 300 + d] = actors[a * 300 + d] * sc;
}

// ---------------------------------------------------------------------------
__global__ __launch_bounds__(64) void k_lse(
    const float* __restrict__ link, float* __restrict__ out) {
  const int a = blockIdx.x;
  const int l = threadIdx.x;
  float v[8];
  float m = -1e30f;
#pragma unroll
  for (int i = 0; i < 8; ++i) {
    v[i] = link[a * 512 + l + i * 64];
    m = fmaxf(m, v[i]);
  }
  for (int off = 32; off; off >>= 1) m = fmaxf(m, __shfl_xor(m, off));
  float ssum = 0.f;
#pragma unroll
  for (int i = 0; i < 8; ++i) ssum += expf(v[i] - m);
  for (int off = 32; off; off >>= 1) ssum += __shfl_xor(ssum, off);
  if (l == 0) out[a] = logf(ssum) + m;
}

// ---------------------------------------------------------------------------
extern "C" void kernel_launch(void* const* d_in, const int* in_sizes, int n_in,
                              void* d_out, int out_size, void* d_ws, size_t ws_size,
                              hipStream_t stream) {
  const float* fast_text = (const float*)d_in[0];
  const float* actor_matrix = (const float*)d_in[1];
  const float* char_table = (const float*)d_in[2];
  const float* w3 = (const float*)d_in[3];
  const float* b3 = (const float*)d_in[4];
  const float* w4 = (const float*)d_in[5];
  const float* b4 = (const float*)d_in[6];
  const float* w5 = (const float*)d_in[7];
  const float* b5 = (const float*)d_in[8];
  const float* Wi_f = (const float*)d_in[9];
  const float* Wh_f = (const float*)d_in[10];
  const float* b_f = (const float*)d_in[11];
  const float* Wi_b = (const float*)d_in[12];
  const float* Wh_b = (const float*)d_in[13];
  const float* b_b = (const float*)d_in[14];
  const float* alpha_W1 = (const float*)d_in[15];
  const float* alpha_b1 = (const float*)d_in[16];
  const float* alpha_W2 = (const float*)d_in[17];
  const float* alpha_b2 = (const float*)d_in[18];
  const float* alpha_w_out = (const float*)d_in[19];
  const float* feat_table = (const float*)d_in[20];
  const float* affine_W = (const float*)d_in[21];
  const float* affine_b = (const float*)d_in[22];
  const int* word_ids = (const int*)d_in[23];
  const int* char_ids = (const int*)d_in[24];
  const int* espans = (const int*)d_in[25];

  float* ws = (float*)d_ws;
  float* lstm_in = ws;                 // 1024*450
  float* xpF = lstm_in + 460800;       // 1024*600
  float* xpB = xpF + 614400;           // 1024*600
  float* keys = xpB + 614400;          // 1024*300
  float* enc = keys + 307200;          // 512*1000
  float* small = enc + 512000;         // 512*300
  float* actN = small + 153600;        // 2000*300

  float* out = (float*)d_out;
  float* score_link = out + 2000;  // 2000 x 512

  k_token<<<1024, 64, 0, stream>>>(fast_text, char_table, w3, b3, w4, b4, w5, b5,
                                   word_ids, char_ids, lstm_in);
  gemm_xproj<<<dim3(16, 20), 256, 0, stream>>>(lstm_in, Wi_f, b_f, Wi_b, b_b,
                                               xpF, xpB);
  k_lstm<<<2, 640, 0, stream>>>(xpF, xpB, Wh_f, Wh_b, keys);
  k_renorm<<<2000, 64, 0, stream>>>(actor_matrix, actN);
  k_span<<<512, 320, 0, stream>>>(keys, lstm_in, alpha_W1, alpha_b1, alpha_W2,
                                  alpha_b2, alpha_w_out, feat_table, espans, enc);
  k_affine<<<128, 320, 0, stream>>>(enc, affine_W, affine_b, small);
  gemm_nt<<<dim3(32, 8), 256, 0, stream>>>(actN, small, nullptr, score_link,
                                           2000, 512, 300);
  k_lse<<<2000, 64, 0, stream>>>(score_link, out);
}

// Round 12
// 1129.567 us; speedup vs baseline: 1.6339x; 1.1395x over previous
//
#include <hip/hip_runtime.h>
#include <math.h>

typedef _Float16 h2f __attribute__((ext_vector_type(2)));

__device__ __forceinline__ float fdot2f(h2f a, h2f b, float c) {
#if __has_builtin(__builtin_amdgcn_fdot2)
  return __builtin_amdgcn_fdot2(a, b, c, false);
#else
  return c + (float)a[0] * (float)b[0] + (float)a[1] * (float)b[1];
#endif
}

// DPP quad_perm cross-lane (VALU pipe): 0xB1 -> lane^1, 0x4E -> lane^2.
template <int CTRL>
__device__ __forceinline__ float dpp_f(float x) {
  union { float f; int i; } u, r;
  u.f = x;
  r.i = __builtin_amdgcn_update_dpp(0, u.i, CTRL, 0xF, 0xF, false);
  return r.f;
}

__device__ __forceinline__ float sigf(float x) {
  return __builtin_amdgcn_rcpf(1.f + __expf(-x));
}
__device__ __forceinline__ float tanh_fast(float x) {
  return 2.f * __builtin_amdgcn_rcpf(1.f + __expf(-2.f * x)) - 1.f;
}

__device__ __forceinline__ int clampi(int v, int lo, int hi) {
  return v < lo ? lo : (v > hi ? hi : v);
}

// ---------------------------------------------------------------------------
// Kernel A: per-token: ft gather + char conv (3,4,5) -> lstm_in[1024][450]
// ---------------------------------------------------------------------------
__global__ __launch_bounds__(64) void k_token(
    const float* __restrict__ fast_text, const float* __restrict__ char_table,
    const float* __restrict__ w3, const float* __restrict__ b3,
    const float* __restrict__ w4, const float* __restrict__ b4,
    const float* __restrict__ w5, const float* __restrict__ b5,
    const int* __restrict__ word_ids, const int* __restrict__ char_ids,
    float* __restrict__ lstm_in) {
  const int t = blockIdx.x;
  const int tid = threadIdx.x;
  __shared__ float ce[16][16];  // ce[l][ci]
  for (int i = tid; i < 256; i += 64) {
    int l = i >> 4, ci = i & 15;
    ce[l][ci] = char_table[char_ids[t * 16 + l] * 16 + ci];
  }
  __syncthreads();
  const int wid = word_ids[t];
  for (int d = tid; d < 300; d += 64)
    lstm_in[t * 450 + d] = fast_text[wid * 300 + d];
  const int f = tid;
  if (f < 50) {
    {
      float acc[14];
#pragma unroll
      for (int p = 0; p < 14; ++p) acc[p] = 0.f;
      for (int ci = 0; ci < 16; ++ci) {
#pragma unroll
        for (int kk = 0; kk < 3; ++kk) {
          float wv = w3[(f * 16 + ci) * 3 + kk];
#pragma unroll
          for (int p = 0; p < 14; ++p) acc[p] += ce[p + kk][ci] * wv;
        }
      }
      float m = acc[0];
#pragma unroll
      for (int p = 1; p < 14; ++p) m = fmaxf(m, acc[p]);
      lstm_in[t * 450 + 300 + f] = fmaxf(0.f, m + b3[f]);
    }
    {
      float acc[13];
#pragma unroll
      for (int p = 0; p < 13; ++p) acc[p] = 0.f;
      for (int ci = 0; ci < 16; ++ci) {
#pragma unroll
        for (int kk = 0; kk < 4; ++kk) {
          float wv = w4[(f * 16 + ci) * 4 + kk];
#pragma unroll
          for (int p = 0; p < 13; ++p) acc[p] += ce[p + kk][ci] * wv;
        }
      }
      float m = acc[0];
#pragma unroll
      for (int p = 1; p < 13; ++p) m = fmaxf(m, acc[p]);
      lstm_in[t * 450 + 350 + f] = fmaxf(0.f, m + b4[f]);
    }
    {
      float acc[12];
#pragma unroll
      for (int p = 0; p < 12; ++p) acc[p] = 0.f;
      for (int ci = 0; ci < 16; ++ci) {
#pragma unroll
        for (int kk = 0; kk < 5; ++kk) {
          float wv = w5[(f * 16 + ci) * 5 + kk];
#pragma unroll
          for (int p = 0; p < 12; ++p) acc[p] += ce[p + kk][ci] * wv;
        }
      }
      float m = acc[0];
#pragma unroll
      for (int p = 1; p < 12; ++p) m = fmaxf(m, acc[p]);
      lstm_in[t * 450 + 400 + f] = fmaxf(0.f, m + b5[f]);
    }
  }
}

// ---------------------------------------------------------------------------
// Generic fp32 GEMM: C[M][N] = A[M][K] @ W[N][K]^T (+ bias[N] if non-null)
// ---------------------------------------------------------------------------
__global__ __launch_bounds__(256) void gemm_nt(
    const float* __restrict__ A, const float* __restrict__ W,
    const float* __restrict__ bias, float* __restrict__ C,
    int M, int N, int K) {
  __shared__ float As[16][64];
  __shared__ float Ws[16][64];
  const int tid = threadIdx.x;
  const int tx = tid & 15, ty = tid >> 4;
  const int r0 = blockIdx.x * 64, c0 = blockIdx.y * 64;
  float acc[4][4] = {};
  for (int k0 = 0; k0 < K; k0 += 16) {
    for (int i = tid; i < 1024; i += 256) {
      int rr = i >> 4, kk = i & 15;
      int r = r0 + rr, k = k0 + kk;
      As[kk][rr] = (r < M && k < K) ? A[r * K + k] : 0.f;
      int c = c0 + rr;
      Ws[kk][rr] = (c < N && k < K) ? W[c * K + k] : 0.f;
    }
    __syncthreads();
#pragma unroll
    for (int kk = 0; kk < 16; ++kk) {
      const float4 av = *(const float4*)(&As[kk][ty * 4]);
      const float4 wv = *(const float4*)(&Ws[kk][tx * 4]);
      float a[4] = {av.x, av.y, av.z, av.w};
      float w[4] = {wv.x, wv.y, wv.z, wv.w};
#pragma unroll
      for (int i = 0; i < 4; ++i)
#pragma unroll
        for (int j = 0; j < 4; ++j) acc[i][j] += a[i] * w[j];
    }
    __syncthreads();
  }
#pragma unroll
  for (int i = 0; i < 4; ++i) {
    int r = r0 + ty * 4 + i;
    if (r >= M) continue;
#pragma unroll
    for (int j = 0; j < 4; ++j) {
      int c = c0 + tx * 4 + j;
      if (c < N) C[r * N + c] = acc[i][j] + (bias ? bias[c] : 0.f);
    }
  }
}

// ---------------------------------------------------------------------------
// Fused xproj GEMM: both directions in one launch.
// ---------------------------------------------------------------------------
__global__ __launch_bounds__(256) void gemm_xproj(
    const float* __restrict__ A,
    const float* __restrict__ Wf, const float* __restrict__ bf,
    const float* __restrict__ Wb, const float* __restrict__ bb,
    float* __restrict__ xpF, float* __restrict__ xpB) {
  const int M = 1024, N = 600, K = 450;
  const bool back = blockIdx.y >= 10;
  const float* __restrict__ W = back ? Wb : Wf;
  const float* __restrict__ bias = back ? bb : bf;
  float* __restrict__ C = back ? xpB : xpF;
  const int yb = back ? (blockIdx.y - 10) : blockIdx.y;

  __shared__ float As[16][64];
  __shared__ float Ws[16][64];
  const int tid = threadIdx.x;
  const int tx = tid & 15, ty = tid >> 4;
  const int r0 = blockIdx.x * 64, c0 = yb * 64;
  float acc[4][4] = {};
  for (int k0 = 0; k0 < K; k0 += 16) {
    for (int i = tid; i < 1024; i += 256) {
      int rr = i >> 4, kk = i & 15;
      int r = r0 + rr, k = k0 + kk;
      As[kk][rr] = (r < M && k < K) ? A[r * K + k] : 0.f;
      int c = c0 + rr;
      Ws[kk][rr] = (c < N && k < K) ? W[c * K + k] : 0.f;
    }
    __syncthreads();
#pragma unroll
    for (int kk = 0; kk < 16; ++kk) {
      const float4 av = *(const float4*)(&As[kk][ty * 4]);
      const float4 wv = *(const float4*)(&Ws[kk][tx * 4]);
      float a[4] = {av.x, av.y, av.z, av.w};
      float w[4] = {wv.x, wv.y, wv.z, wv.w};
#pragma unroll
      for (int i = 0; i < 4; ++i)
#pragma unroll
        for (int j = 0; j < 4; ++j) acc[i][j] += a[i] * w[j];
    }
    __syncthreads();
  }
#pragma unroll
  for (int i = 0; i < 4; ++i) {
    int r = r0 + ty * 4 + i;
#pragma unroll
    for (int j = 0; j < 4; ++j) {
      int c = c0 + tx * 4 + j;
      if (c < N) C[r * N + c] = acc[i][j] + bias[c];
    }
  }
}

// ---------------------------------------------------------------------------
// Kernel C: LSTM recurrence, one block per direction. Split-K4 (r8 body,
// measured best 860us): thread (u = tid>>2, g = tid&3) computes partials of
// all 4 gate rows of unit u over k-quarter g (5 ds_read_b128/thread/step).
// 2-stage DPP quad reduce completes the sums; thread g ends owning row
// g*150+u.
// Register-budget fix (r11): the backend derives the per-wave VGPR budget
// from LDS-limited occupancy. With 1KB LDS it assumed many blocks/CU ->
// budget 84 -> ~16 weight regs spilled to scratch (the persistent ~2000
// cy/step wall). A 100KB LDS pad caps occupancy at 1 block/CU -> 3 waves/
// busiest-SIMD -> budget ~170. The pad must be un-DCE-able: store + 
// dependent load escaping to global, behind blockIdx.x>=2 (grid is 2 at
// runtime -- never executes, but unprovable at compile time). Runtime cost
// zero: only 2 blocks exist on 256 CUs, so real co-residency is unchanged.
// ---------------------------------------------------------------------------
__global__ __launch_bounds__(640, 1) void k_lstm(
    const float* __restrict__ xprojF, const float* __restrict__ xprojB,
    const float* __restrict__ Wh_f, const float* __restrict__ Wh_b,
    float* __restrict__ keys) {
  const int dir = blockIdx.x;
  const float* __restrict__ xp = dir ? xprojB : xprojF;
  const float* __restrict__ Wh = dir ? Wh_b : Wh_f;
  const int tid = threadIdx.x;
  const int u = tid >> 2;                  // hidden unit (active < 150)
  const int g = tid & 3;                   // k-quarter / final gate row
  const int uu = u < 150 ? u : 149;        // clamped for safe addressing
  const int row = g * 150 + uu;
  const bool act = (tid < 600);

  __shared__ alignas(16) h2f hbuf[2][80];  // h packed f16: 150 + 10 zero pad
  __shared__ float ldspad[25600];          // 100 KB occupancy limiter

  // Un-DCE-able pad use: never executes (grid is (2,1,1)) but the compiler
  // cannot prove blockIdx.x < 2, and the load feeding a global store keeps
  // both the store and the array alive.
  if ((int)blockIdx.x >= 2) {
    ldspad[tid] = (float)tid;
    keys[tid] = ldspad[tid] + ldspad[(tid * 3 + 1) % 25600];
  }

  // weights: 4 gate rows x 20 h2f covering halfs [40g, 40g+40)
  h2f w0[20], w1[20], w2[20], w3[20];
  {
    const float* R0 = Wh + (0 * 150 + uu) * 150;
    const float* R1 = Wh + (1 * 150 + uu) * 150;
    const float* R2 = Wh + (2 * 150 + uu) * 150;
    const float* R3 = Wh + (3 * 150 + uu) * 150;
#pragma unroll
    for (int kk = 0; kk < 20; ++kk) {
      const int k = 40 * g + 2 * kk;
      float a0 = 0.f, a1 = 0.f, b0 = 0.f, b1 = 0.f;
      float c0 = 0.f, c1 = 0.f, d0 = 0.f, d1 = 0.f;
      if (k < 150) {  // k even -> k+1 <= 149 also valid
        float2 p;
        p = *(const float2*)(R0 + k); a0 = p.x; a1 = p.y;
        p = *(const float2*)(R1 + k); b0 = p.x; b1 = p.y;
        p = *(const float2*)(R2 + k); c0 = p.x; c1 = p.y;
        p = *(const float2*)(R3 + k); d0 = p.x; d1 = p.y;
      }
      h2f v;
      v[0] = (_Float16)a0; v[1] = (_Float16)a1; w0[kk] = v;
      v[0] = (_Float16)b0; v[1] = (_Float16)b1; w1[kk] = v;
      v[0] = (_Float16)c0; v[1] = (_Float16)c1; w2[kk] = v;
      v[0] = (_Float16)d0; v[1] = (_Float16)d1; w3[kk] = v;
    }
  }
  for (int i = tid; i < 160; i += 640) {
    h2f z;
    z[0] = (_Float16)0.f;
    z[1] = (_Float16)0.f;
    hbuf[i / 80][i % 80] = z;
  }
  float c = 0.f;
  float xv = xp[(dir ? 1023 : 0) * 600 + row];
  __syncthreads();

  int cur = 0;
  for (int step = 0; step < 1024; ++step) {
    const int t = dir ? (1023 - step) : step;
    const int tn = dir ? (t > 0 ? t - 1 : 0) : (t < 1023 ? t + 1 : 1023);
    // prefetch next step's xp (hidden under the dot chain)
    const float xv_next = xp[tn * 600 + row];
    // 5 ds_read_b128 of this thread's k-quarter (4 broadcast groups/wave)
    const float4* hv = (const float4*)hbuf[cur] + 5 * g;
    float a0 = 0.f, a1 = 0.f, a2 = 0.f, a3 = 0.f;
#pragma unroll
    for (int i = 0; i < 5; ++i) {
      float4 q = hv[i];
      const h2f* hh = (const h2f*)&q;
#pragma unroll
      for (int m = 0; m < 4; ++m) {
        a0 = fdot2f(w0[4 * i + m], hh[m], a0);
        a1 = fdot2f(w1[4 * i + m], hh[m], a1);
        a2 = fdot2f(w2[4 * i + m], hh[m], a2);
        a3 = fdot2f(w3[4 * i + m], hh[m], a3);
      }
    }
    // stage 1: sum quarters {g, g^1} for each row
    const float e0 = a0 + dpp_f<0xB1>(a0);
    const float e1 = a1 + dpp_f<0xB1>(a1);
    const float e2 = a2 + dpp_f<0xB1>(a2);
    const float e3 = a3 + dpp_f<0xB1>(a3);
    const float fa = (g & 1) ? e1 : e0;
    const float fb = (g & 1) ? e3 : e2;
    // stage 2: sum quarters {g^2, g^3}
    const float ga_ = fa + dpp_f<0x4E>(fa);
    const float gb_ = fb + dpp_f<0x4E>(fb);
    const float z = ((g & 2) ? gb_ : ga_) + xv;
    xv = xv_next;
    // nonlinearity: sigmoid for i,f,o; tanh for g
    const float zz = (g == 2) ? 2.f * z : z;
    const float s = sigf(zz);
    const float val = (g == 2) ? (2.f * s - 1.f) : s;
    // gate exchange within the quad (DPP)
    const float v1 = dpp_f<0xB1>(val);  // at g0: f
    const float gv = dpp_f<0x4E>(val);  // at g0: g
    const float ov = dpp_f<0x4E>(v1);   // at g0: o
    if (act && g == 0) {
      c = v1 * c + val * gv;
      const float h = ov * tanh_fast(c);
      keys[t * 300 + dir * 150 + u] = h;
      ((_Float16*)hbuf[cur ^ 1])[u] = (_Float16)h;
    }
    cur ^= 1;
    __syncthreads();
  }
}

// ---------------------------------------------------------------------------
// Kernel D: span scorer -> enc[512][1000]
// ---------------------------------------------------------------------------
__global__ __launch_bounds__(320) void k_span(
    const float* __restrict__ keys, const float* __restrict__ lstm_in,
    const float* __restrict__ W1, const float* __restrict__ b1,
    const float* __restrict__ W2, const float* __restrict__ b2,
    const float* __restrict__ w_out, const float* __restrict__ feat_table,
    const int* __restrict__ espans, float* __restrict__ enc) {
  const int e = blockIdx.x;
  const int tid = threadIdx.x;
  const int s = espans[e * 4 + 0];
  const int en = espans[e * 4 + 1];
  const int f0 = espans[e * 4 + 2];
  const int f1 = espans[e * 4 + 3];

  __shared__ float ksh[10][300];
  __shared__ float hsh[10][152];
  __shared__ float h2sh[10][152];
  __shared__ float att[10];
  __shared__ float scl[2];

  for (int i = tid; i < 3000; i += 320) {
    int p = i / 300, d = i % 300;
    int row = clampi(s + p, 0, 1023);
    ksh[p][d] = keys[row * 300 + d];
  }
  __syncthreads();

  if (tid < 152) {
    int jj = tid;
    if (jj < 150) {
      float acc[10];
#pragma unroll
      for (int p = 0; p < 10; ++p) acc[p] = b1[jj];
      for (int k = 0; k < 300; k += 4) {
        float w0 = W1[(k + 0) * 150 + jj];
        float w1 = W1[(k + 1) * 150 + jj];
        float w2 = W1[(k + 2) * 150 + jj];
        float w3 = W1[(k + 3) * 150 + jj];
#pragma unroll
        for (int p = 0; p < 10; ++p) {
          const float4 kv = *(const float4*)(&ksh[p][k]);
          acc[p] += kv.x * w0 + kv.y * w1 + kv.z * w2 + kv.w * w3;
        }
      }
#pragma unroll
      for (int p = 0; p < 10; ++p) hsh[p][jj] = fmaxf(acc[p], 0.f);
    } else {
#pragma unroll
      for (int p = 0; p < 10; ++p) hsh[p][jj] = 0.f;
    }
  }
  __syncthreads();

  if (tid < 150) {
    int jj = tid;
    float acc[10];
#pragma unroll
    for (int p = 0; p < 10; ++p) acc[p] = b2[jj];
    for (int k = 0; k < 152; k += 4) {
      float w0 = (k + 0 < 150) ? W2[(k + 0) * 150 + jj] : 0.f;
      float w1 = (k + 1 < 150) ? W2[(k + 1) * 150 + jj] : 0.f;
      float w2 = (k + 2 < 150) ? W2[(k + 2) * 150 + jj] : 0.f;
      float w3 = (k + 3 < 150) ? W2[(k + 3) * 150 + jj] : 0.f;
#pragma unroll
      for (int p = 0; p < 10; ++p) {
        const float4 hv = *(const float4*)(&hsh[p][k]);
        acc[p] += hv.x * w0 + hv.y * w1 + hv.z * w2 + hv.w * w3;
      }
    }
#pragma unroll
    for (int p = 0; p < 10; ++p) h2sh[p][jj] = fmaxf(acc[p], 0.f);
  }
  __syncthreads();

  if (tid < 10) {
    float lg = -1e30f;
    if (tid < en - s) {
      float d = 0.f;
      for (int k = 0; k < 150; ++k) d += h2sh[tid][k] * w_out[k];
      lg = d;
    }
    att[tid] = lg;
  }
  if (tid >= 64 && tid < 66) {
    int r = tid - 64;
    int fi = (r == 0) ? f0 : f1;
    float nsq = 0.f;
    for (int k = 0; k < 50; ++k) {
      float v = feat_table[fi * 50 + k];
      nsq += v * v;
    }
    float n = sqrtf(nsq);
    scl[r] = fminf(1.f, 1.f / fmaxf(n, 1e-7f));
  }
  __syncthreads();

  if (tid == 0) {
    float m = -1e30f;
    for (int p = 0; p < 10; ++p) m = fmaxf(m, att[p]);
    float ex[10];
    float ssum = 0.f;
    for (int p = 0; p < 10; ++p) {
      ex[p] = expf(att[p] - m);
      ssum += ex[p];
    }
    for (int p = 0; p < 10; ++p) att[p] = ex[p] / ssum;
  }
  __syncthreads();

  if (tid < 300) {
    int d = tid;
    float xf = keys[s * 300 + d];
    float xl = keys[(en - 1) * 300 + d];
    float xh = 0.f;
#pragma unroll
    for (int p = 0; p < 10; ++p) {
      int row = clampi(s + p, 0, 1023);
      xh += att[p] * lstm_in[row * 450 + d];
    }
    enc[e * 1000 + d] = xf;
    enc[e * 1000 + 300 + d] = xl;
    enc[e * 1000 + 600 + d] = xh;
  }
  if (tid < 100) {
    int r = tid / 50, cc = tid % 50;
    int fi = (r == 0) ? f0 : f1;
    enc[e * 1000 + 900 + tid] = feat_table[fi * 50 + cc] * scl[r];
  }
}

// ---------------------------------------------------------------------------
// Kernel E: small = enc @ affine_W + affine_b   (4 spans per block)
// ---------------------------------------------------------------------------
__global__ __launch_bounds__(320) void k_affine(
    const float* __restrict__ enc, const float* __restrict__ W,
    const float* __restrict__ bias, float* __restrict__ small) {
  const int e0 = blockIdx.x * 4;
  const int tid = threadIdx.x;
  __shared__ float es[4][1000];
  for (int i = tid; i < 4000; i += 320) es[i / 1000][i % 1000] = enc[e0 * 1000 + i];
  __syncthreads();
  if (tid < 300) {
    float a0 = bias[tid], a1 = bias[tid], a2 = bias[tid], a3 = bias[tid];
    for (int k = 0; k < 1000; k += 4) {
      float w0 = W[(k + 0) * 300 + tid];
      float w1 = W[(k + 1) * 300 + tid];
      float w2 = W[(k + 2) * 300 + tid];
      float w3 = W[(k + 3) * 300 + tid];
      const float4 v0 = *(const float4*)(&es[0][k]);
      const float4 v1 = *(const float4*)(&es[1][k]);
      const float4 v2 = *(const float4*)(&es[2][k]);
      const float4 v3 = *(const float4*)(&es[3][k]);
      a0 += v0.x * w0 + v0.y * w1 + v0.z * w2 + v0.w * w3;
      a1 += v1.x * w0 + v1.y * w1 + v1.z * w2 + v1.w * w3;
      a2 += v2.x * w0 + v2.y * w1 + v2.z * w2 + v2.w * w3;
      a3 += v3.x * w0 + v3.y * w1 + v3.z * w2 + v3.w * w3;
    }
    small[(e0 + 0) * 300 + tid] = a0;
    small[(e0 + 1) * 300 + tid] = a1;
    small[(e0 + 2) * 300 + tid] = a2;
    small[(e0 + 3) * 300 + tid] = a3;
  }
}

// ---------------------------------------------------------------------------
__global__ __launch_bounds__(64) void k_renorm(
    const float* __restrict__ actors, float* __restrict__ actorsN) {
  const int a = blockIdx.x;
  const int l = threadIdx.x;
  float nsq = 0.f;
  for (int d = l; d < 300; d += 64) {
    float v = actors[a * 300 + d];
    nsq += v * v;
  }
  for (int off = 32; off; off >>= 1) nsq += __shfl_down(nsq, off);
  nsq = __shfl(nsq, 0);
  float sc = fminf(1.f, 1.f / fmaxf(sqrtf(nsq), 1e-7f));
  for (int d = l; d < 300; d += 64) actorsN[a * 300 + d] = actors[a * 300 + d] * sc;
}

// ---------------------------------------------------------------------------
__global__ __launch_bounds__(64) void k_lse(
    const float* __restrict__ link, float* __restrict__ out) {
  const int a = blockIdx.x;
  const int l = threadIdx.x;
  float v[8];
  float m = -1e30f;
#pragma unroll
  for (int i = 0; i < 8; ++i) {
    v[i] = link[a * 512 + l + i * 64];
    m = fmaxf(m, v[i]);
  }
  for (int off = 32; off; off >>= 1) m = fmaxf(m, __shfl_xor(m, off));
  float ssum = 0.f;
#pragma unroll
  for (int i = 0; i < 8; ++i) ssum += expf(v[i] - m);
  for (int off = 32; off; off >>= 1) ssum += __shfl_xor(ssum, off);
  if (l == 0) out[a] = logf(ssum) + m;
}

// ---------------------------------------------------------------------------
extern "C" void kernel_launch(void* const* d_in, const int* in_sizes, int n_in,
                              void* d_out, int out_size, void* d_ws, size_t ws_size,
                              hipStream_t stream) {
  const float* fast_text = (const float*)d_in[0];
  const float* actor_matrix = (const float*)d_in[1];
  const float* char_table = (const float*)d_in[2];
  const float* w3 = (const float*)d_in[3];
  const float* b3 = (const float*)d_in[4];
  const float* w4 = (const float*)d_in[5];
  const float* b4 = (const float*)d_in[6];
  const float* w5 = (const float*)d_in[7];
  const float* b5 = (const float*)d_in[8];
  const float* Wi_f = (const float*)d_in[9];
  const float* Wh_f = (const float*)d_in[10];
  const float* b_f = (const float*)d_in[11];
  const float* Wi_b = (const float*)d_in[12];
  const float* Wh_b = (const float*)d_in[13];
  const float* b_b = (const float*)d_in[14];
  const float* alpha_W1 = (const float*)d_in[15];
  const float* alpha_b1 = (const float*)d_in[16];
  const float* alpha_W2 = (const float*)d_in[17];
  const float* alpha_b2 = (const float*)d_in[18];
  const float* alpha_w_out = (const float*)d_in[19];
  const float* feat_table = (const float*)d_in[20];
  const float* affine_W = (const float*)d_in[21];
  const float* affine_b = (const float*)d_in[22];
  const int* word_ids = (const int*)d_in[23];
  const int* char_ids = (const int*)d_in[24];
  const int* espans = (const int*)d_in[25];

  float* ws = (float*)d_ws;
  float* lstm_in = ws;                 // 1024*450
  float* xpF = lstm_in + 460800;       // 1024*600
  float* xpB = xpF + 614400;           // 1024*600
  float* keys = xpB + 614400;          // 1024*300
  float* enc = keys + 307200;          // 512*1000
  float* small = enc + 512000;         // 512*300
  float* actN = small + 153600;        // 2000*300

  float* out = (float*)d_out;
  float* score_link = out + 2000;  // 2000 x 512

  k_token<<<1024, 64, 0, stream>>>(fast_text, char_table, w3, b3, w4, b4, w5, b5,
                                   word_ids, char_ids, lstm_in);
  gemm_xproj<<<dim3(16, 20), 256, 0, stream>>>(lstm_in, Wi_f, b_f, Wi_b, b_b,
                                               xpF, xpB);
  k_lstm<<<2, 640, 0, stream>>>(xpF, xpB, Wh_f, Wh_b, keys);
  k_renorm<<<2000, 64, 0, stream>>>(actor_matrix, actN);
  k_span<<<512, 320, 0, stream>>>(keys, lstm_in, alpha_W1, alpha_b1, alpha_W2,
                                  alpha_b2, alpha_w_out, feat_table, espans, enc);
  k_affine<<<128, 320, 0, stream>>>(enc, affine_W, affine_b, small);
  gemm_nt<<<dim3(32, 8), 256, 0, stream>>>(actN, small, nullptr, score_link,
                                           2000, 512, 300);
  k_lse<<<2000, 64, 0, stream>>>(score_link, out);
}

// Round 13
// 1128.573 us; speedup vs baseline: 1.6353x; 1.0009x over previous
//
#include <hip/hip_runtime.h>
#include <math.h>

typedef _Float16 h2f __attribute__((ext_vector_type(2)));

__device__ __forceinline__ float fdot2f(h2f a, h2f b, float c) {
#if __has_builtin(__builtin_amdgcn_fdot2)
  return __builtin_amdgcn_fdot2(a, b, c, false);
#else
  return c + (float)a[0] * (float)b[0] + (float)a[1] * (float)b[1];
#endif
}

// DPP quad_perm cross-lane (VALU pipe): 0xB1 -> lane^1, 0x4E -> lane^2.
template <int CTRL>
__device__ __forceinline__ float dpp_f(float x) {
  union { float f; int i; } u, r;
  u.f = x;
  r.i = __builtin_amdgcn_update_dpp(0, u.i, CTRL, 0xF, 0xF, false);
  return r.f;
}

__device__ __forceinline__ float sigf(float x) {
  return __builtin_amdgcn_rcpf(1.f + __expf(-x));
}
__device__ __forceinline__ float tanh_fast(float x) {
  return 2.f * __builtin_amdgcn_rcpf(1.f + __expf(-2.f * x)) - 1.f;
}

__device__ __forceinline__ int clampi(int v, int lo, int hi) {
  return v < lo ? lo : (v > hi ? hi : v);
}

// ---------------------------------------------------------------------------
// Kernel A: per-token: ft gather + char conv (3,4,5) -> lstm_in[1024][450]
// ---------------------------------------------------------------------------
__global__ __launch_bounds__(64) void k_token(
    const float* __restrict__ fast_text, const float* __restrict__ char_table,
    const float* __restrict__ w3, const float* __restrict__ b3,
    const float* __restrict__ w4, const float* __restrict__ b4,
    const float* __restrict__ w5, const float* __restrict__ b5,
    const int* __restrict__ word_ids, const int* __restrict__ char_ids,
    float* __restrict__ lstm_in) {
  const int t = blockIdx.x;
  const int tid = threadIdx.x;
  __shared__ float ce[16][16];  // ce[l][ci]
  for (int i = tid; i < 256; i += 64) {
    int l = i >> 4, ci = i & 15;
    ce[l][ci] = char_table[char_ids[t * 16 + l] * 16 + ci];
  }
  __syncthreads();
  const int wid = word_ids[t];
  for (int d = tid; d < 300; d += 64)
    lstm_in[t * 450 + d] = fast_text[wid * 300 + d];
  const int f = tid;
  if (f < 50) {
    {
      float acc[14];
#pragma unroll
      for (int p = 0; p < 14; ++p) acc[p] = 0.f;
      for (int ci = 0; ci < 16; ++ci) {
#pragma unroll
        for (int kk = 0; kk < 3; ++kk) {
          float wv = w3[(f * 16 + ci) * 3 + kk];
#pragma unroll
          for (int p = 0; p < 14; ++p) acc[p] += ce[p + kk][ci] * wv;
        }
      }
      float m = acc[0];
#pragma unroll
      for (int p = 1; p < 14; ++p) m = fmaxf(m, acc[p]);
      lstm_in[t * 450 + 300 + f] = fmaxf(0.f, m + b3[f]);
    }
    {
      float acc[13];
#pragma unroll
      for (int p = 0; p < 13; ++p) acc[p] = 0.f;
      for (int ci = 0; ci < 16; ++ci) {
#pragma unroll
        for (int kk = 0; kk < 4; ++kk) {
          float wv = w4[(f * 16 + ci) * 4 + kk];
#pragma unroll
          for (int p = 0; p < 13; ++p) acc[p] += ce[p + kk][ci] * wv;
        }
      }
      float m = acc[0];
#pragma unroll
      for (int p = 1; p < 13; ++p) m = fmaxf(m, acc[p]);
      lstm_in[t * 450 + 350 + f] = fmaxf(0.f, m + b4[f]);
    }
    {
      float acc[12];
#pragma unroll
      for (int p = 0; p < 12; ++p) acc[p] = 0.f;
      for (int ci = 0; ci < 16; ++ci) {
#pragma unroll
        for (int kk = 0; kk < 5; ++kk) {
          float wv = w5[(f * 16 + ci) * 5 + kk];
#pragma unroll
          for (int p = 0; p < 12; ++p) acc[p] += ce[p + kk][ci] * wv;
        }
      }
      float m = acc[0];
#pragma unroll
      for (int p = 1; p < 12; ++p) m = fmaxf(m, acc[p]);
      lstm_in[t * 450 + 400 + f] = fmaxf(0.f, m + b5[f]);
    }
  }
}

// ---------------------------------------------------------------------------
// Generic fp32 GEMM: C[M][N] = A[M][K] @ W[N][K]^T (+ bias[N] if non-null)
// ---------------------------------------------------------------------------
__global__ __launch_bounds__(256) void gemm_nt(
    const float* __restrict__ A, const float* __restrict__ W,
    const float* __restrict__ bias, float* __restrict__ C,
    int M, int N, int K) {
  __shared__ float As[16][64];
  __shared__ float Ws[16][64];
  const int tid = threadIdx.x;
  const int tx = tid & 15, ty = tid >> 4;
  const int r0 = blockIdx.x * 64, c0 = blockIdx.y * 64;
  float acc[4][4] = {};
  for (int k0 = 0; k0 < K; k0 += 16) {
    for (int i = tid; i < 1024; i += 256) {
      int rr = i >> 4, kk = i & 15;
      int r = r0 + rr, k = k0 + kk;
      As[kk][rr] = (r < M && k < K) ? A[r * K + k] : 0.f;
      int c = c0 + rr;
      Ws[kk][rr] = (c < N && k < K) ? W[c * K + k] : 0.f;
    }
    __syncthreads();
#pragma unroll
    for (int kk = 0; kk < 16; ++kk) {
      const float4 av = *(const float4*)(&As[kk][ty * 4]);
      const float4 wv = *(const float4*)(&Ws[kk][tx * 4]);
      float a[4] = {av.x, av.y, av.z, av.w};
      float w[4] = {wv.x, wv.y, wv.z, wv.w};
#pragma unroll
      for (int i = 0; i < 4; ++i)
#pragma unroll
        for (int j = 0; j < 4; ++j) acc[i][j] += a[i] * w[j];
    }
    __syncthreads();
  }
#pragma unroll
  for (int i = 0; i < 4; ++i) {
    int r = r0 + ty * 4 + i;
    if (r >= M) continue;
#pragma unroll
    for (int j = 0; j < 4; ++j) {
      int c = c0 + tx * 4 + j;
      if (c < N) C[r * N + c] = acc[i][j] + (bias ? bias[c] : 0.f);
    }
  }
}

// ---------------------------------------------------------------------------
// Fused xproj GEMM: both directions in one launch.
// ---------------------------------------------------------------------------
__global__ __launch_bounds__(256) void gemm_xproj(
    const float* __restrict__ A,
    const float* __restrict__ Wf, const float* __restrict__ bf,
    const float* __restrict__ Wb, const float* __restrict__ bb,
    float* __restrict__ xpF, float* __restrict__ xpB) {
  const int M = 1024, N = 600, K = 450;
  const bool back = blockIdx.y >= 10;
  const float* __restrict__ W = back ? Wb : Wf;
  const float* __restrict__ bias = back ? bb : bf;
  float* __restrict__ C = back ? xpB : xpF;
  const int yb = back ? (blockIdx.y - 10) : blockIdx.y;

  __shared__ float As[16][64];
  __shared__ float Ws[16][64];
  const int tid = threadIdx.x;
  const int tx = tid & 15, ty = tid >> 4;
  const int r0 = blockIdx.x * 64, c0 = yb * 64;
  float acc[4][4] = {};
  for (int k0 = 0; k0 < K; k0 += 16) {
    for (int i = tid; i < 1024; i += 256) {
      int rr = i >> 4, kk = i & 15;
      int r = r0 + rr, k = k0 + kk;
      As[kk][rr] = (r < M && k < K) ? A[r * K + k] : 0.f;
      int c = c0 + rr;
      Ws[kk][rr] = (c < N && k < K) ? W[c * K + k] : 0.f;
    }
    __syncthreads();
#pragma unroll
    for (int kk = 0; kk < 16; ++kk) {
      const float4 av = *(const float4*)(&As[kk][ty * 4]);
      const float4 wv = *(const float4*)(&Ws[kk][tx * 4]);
      float a[4] = {av.x, av.y, av.z, av.w};
      float w[4] = {wv.x, wv.y, wv.z, wv.w};
#pragma unroll
      for (int i = 0; i < 4; ++i)
#pragma unroll
        for (int j = 0; j < 4; ++j) acc[i][j] += a[i] * w[j];
    }
    __syncthreads();
  }
#pragma unroll
  for (int i = 0; i < 4; ++i) {
    int r = r0 + ty * 4 + i;
#pragma unroll
    for (int j = 0; j < 4; ++j) {
      int c = c0 + tx * 4 + j;
      if (c < N) C[r * N + c] = acc[i][j] + bias[c];
    }
  }
}

// ---------------------------------------------------------------------------
// Kernel C: LSTM recurrence, one block per direction. Split-K4 (r8 body,
// measured best): thread (u = tid>>2, g = tid&3) computes partials of all
// 4 gate rows of unit u over k-quarter g (5 ds_read_b128/thread/step).
// 2-stage DPP quad reduce completes the sums; thread g ends owning row
// g*150+u.
// Register fix attempt #5 (r13): every INDIRECT knob failed to move the
// allocator off its 84-VGPR target (launch_bounds min-waves: 84/108;
// waves_per_eu(3,3): 84; waves_per_eu(1,1): 164-cap; 100KB LDS pad with
// surviving allocation: still 84). amdgpu_num_vgpr(128) is the DIRECT
// allocation request: peak live need ~105 <= 128, and 3 waves x 128 = 384
// <= 512/SIMD so the 10-wave block still fits 1 block/CU (grid is only 2
// blocks anyway). Expect VGPR_Count = ~128 and the ~16-reg spill-reload
// per loop iteration (the stable ~2060 cy/step wall) to vanish.
// ---------------------------------------------------------------------------
__attribute__((amdgpu_num_vgpr(128)))
__global__ __launch_bounds__(640, 1) void k_lstm(
    const float* __restrict__ xprojF, const float* __restrict__ xprojB,
    const float* __restrict__ Wh_f, const float* __restrict__ Wh_b,
    float* __restrict__ keys) {
  const int dir = blockIdx.x;
  const float* __restrict__ xp = dir ? xprojB : xprojF;
  const float* __restrict__ Wh = dir ? Wh_b : Wh_f;
  const int tid = threadIdx.x;
  const int u = tid >> 2;                  // hidden unit (active < 150)
  const int g = tid & 3;                   // k-quarter / final gate row
  const int uu = u < 150 ? u : 149;        // clamped for safe addressing
  const int row = g * 150 + uu;
  const bool act = (tid < 600);

  __shared__ alignas(16) h2f hbuf[2][80];  // h packed f16: 150 + 10 zero pad

  // weights: 4 gate rows x 20 h2f covering halfs [40g, 40g+40)
  h2f w0[20], w1[20], w2[20], w3[20];
  {
    const float* R0 = Wh + (0 * 150 + uu) * 150;
    const float* R1 = Wh + (1 * 150 + uu) * 150;
    const float* R2 = Wh + (2 * 150 + uu) * 150;
    const float* R3 = Wh + (3 * 150 + uu) * 150;
#pragma unroll
    for (int kk = 0; kk < 20; ++kk) {
      const int k = 40 * g + 2 * kk;
      float a0 = 0.f, a1 = 0.f, b0 = 0.f, b1 = 0.f;
      float c0 = 0.f, c1 = 0.f, d0 = 0.f, d1 = 0.f;
      if (k < 150) {  // k even -> k+1 <= 149 also valid
        float2 p;
        p = *(const float2*)(R0 + k); a0 = p.x; a1 = p.y;
        p = *(const float2*)(R1 + k); b0 = p.x; b1 = p.y;
        p = *(const float2*)(R2 + k); c0 = p.x; c1 = p.y;
        p = *(const float2*)(R3 + k); d0 = p.x; d1 = p.y;
      }
      h2f v;
      v[0] = (_Float16)a0; v[1] = (_Float16)a1; w0[kk] = v;
      v[0] = (_Float16)b0; v[1] = (_Float16)b1; w1[kk] = v;
      v[0] = (_Float16)c0; v[1] = (_Float16)c1; w2[kk] = v;
      v[0] = (_Float16)d0; v[1] = (_Float16)d1; w3[kk] = v;
    }
  }
  for (int i = tid; i < 160; i += 640) {
    h2f z;
    z[0] = (_Float16)0.f;
    z[1] = (_Float16)0.f;
    hbuf[i / 80][i % 80] = z;
  }
  float c = 0.f;
  float xv = xp[(dir ? 1023 : 0) * 600 + row];
  __syncthreads();

  int cur = 0;
  for (int step = 0; step < 1024; ++step) {
    const int t = dir ? (1023 - step) : step;
    const int tn = dir ? (t > 0 ? t - 1 : 0) : (t < 1023 ? t + 1 : 1023);
    // prefetch next step's xp (hidden under the dot chain)
    const float xv_next = xp[tn * 600 + row];
    // 5 ds_read_b128 of this thread's k-quarter (4 broadcast groups/wave)
    const float4* hv = (const float4*)hbuf[cur] + 5 * g;
    float a0 = 0.f, a1 = 0.f, a2 = 0.f, a3 = 0.f;
#pragma unroll
    for (int i = 0; i < 5; ++i) {
      float4 q = hv[i];
      const h2f* hh = (const h2f*)&q;
#pragma unroll
      for (int m = 0; m < 4; ++m) {
        a0 = fdot2f(w0[4 * i + m], hh[m], a0);
        a1 = fdot2f(w1[4 * i + m], hh[m], a1);
        a2 = fdot2f(w2[4 * i + m], hh[m], a2);
        a3 = fdot2f(w3[4 * i + m], hh[m], a3);
      }
    }
    // stage 1: sum quarters {g, g^1} for each row
    const float e0 = a0 + dpp_f<0xB1>(a0);
    const float e1 = a1 + dpp_f<0xB1>(a1);
    const float e2 = a2 + dpp_f<0xB1>(a2);
    const float e3 = a3 + dpp_f<0xB1>(a3);
    const float fa = (g & 1) ? e1 : e0;
    const float fb = (g & 1) ? e3 : e2;
    // stage 2: sum quarters {g^2, g^3}
    const float ga_ = fa + dpp_f<0x4E>(fa);
    const float gb_ = fb + dpp_f<0x4E>(fb);
    const float z = ((g & 2) ? gb_ : ga_) + xv;
    xv = xv_next;
    // nonlinearity: sigmoid for i,f,o; tanh for g
    const float zz = (g == 2) ? 2.f * z : z;
    const float s = sigf(zz);
    const float val = (g == 2) ? (2.f * s - 1.f) : s;
    // gate exchange within the quad (DPP)
    const float v1 = dpp_f<0xB1>(val);  // at g0: f
    const float gv = dpp_f<0x4E>(val);  // at g0: g
    const float ov = dpp_f<0x4E>(v1);   // at g0: o
    if (act && g == 0) {
      c = v1 * c + val * gv;
      const float h = ov * tanh_fast(c);
      keys[t * 300 + dir * 150 + u] = h;
      ((_Float16*)hbuf[cur ^ 1])[u] = (_Float16)h;
    }
    cur ^= 1;
    __syncthreads();
  }
}

// ---------------------------------------------------------------------------
// Kernel D: span scorer -> enc[512][1000]
// ---------------------------------------------------------------------------
__global__ __launch_bounds__(320) void k_span(
    const float* __restrict__ keys, const float* __restrict__ lstm_in,
    const float* __restrict__ W1, const float* __restrict__ b1,
    const float* __restrict__ W2, const float* __restrict__ b2,
    const float* __restrict__ w_out, const float* __restrict__ feat_table,
    const int* __restrict__ espans, float* __restrict__ enc) {
  const int e = blockIdx.x;
  const int tid = threadIdx.x;
  const int s = espans[e * 4 + 0];
  const int en = espans[e * 4 + 1];
  const int f0 = espans[e * 4 + 2];
  const int f1 = espans[e * 4 + 3];

  __shared__ float ksh[10][300];
  __shared__ float hsh[10][152];
  __shared__ float h2sh[10][152];
  __shared__ float att[10];
  __shared__ float scl[2];

  for (int i = tid; i < 3000; i += 320) {
    int p = i / 300, d = i % 300;
    int row = clampi(s + p, 0, 1023);
    ksh[p][d] = keys[row * 300 + d];
  }
  __syncthreads();

  if (tid < 152) {
    int jj = tid;
    if (jj < 150) {
      float acc[10];
#pragma unroll
      for (int p = 0; p < 10; ++p) acc[p] = b1[jj];
      for (int k = 0; k < 300; k += 4) {
        float w0 = W1[(k + 0) * 150 + jj];
        float w1 = W1[(k + 1) * 150 + jj];
        float w2 = W1[(k + 2) * 150 + jj];
        float w3 = W1[(k + 3) * 150 + jj];
#pragma unroll
        for (int p = 0; p < 10; ++p) {
          const float4 kv = *(const float4*)(&ksh[p][k]);
          acc[p] += kv.x * w0 + kv.y * w1 + kv.z * w2 + kv.w * w3;
        }
      }
#pragma unroll
      for (int p = 0; p < 10; ++p) hsh[p][jj] = fmaxf(acc[p], 0.f);
    } else {
#pragma unroll
      for (int p = 0; p < 10; ++p) hsh[p][jj] = 0.f;
    }
  }
  __syncthreads();

  if (tid < 150) {
    int jj = tid;
    float acc[10];
#pragma unroll
    for (int p = 0; p < 10; ++p) acc[p] = b2[jj];
    for (int k = 0; k < 152; k += 4) {
      float w0 = (k + 0 < 150) ? W2[(k + 0) * 150 + jj] : 0.f;
      float w1 = (k + 1 < 150) ? W2[(k + 1) * 150 + jj] : 0.f;
      float w2 = (k + 2 < 150) ? W2[(k + 2) * 150 + jj] : 0.f;
      float w3 = (k + 3 < 150) ? W2[(k + 3) * 150 + jj] : 0.f;
#pragma unroll
      for (int p = 0; p < 10; ++p) {
        const float4 hv = *(const float4*)(&hsh[p][k]);
        acc[p] += hv.x * w0 + hv.y * w1 + hv.z * w2 + hv.w * w3;
      }
    }
#pragma unroll
    for (int p = 0; p < 10; ++p) h2sh[p][jj] = fmaxf(acc[p], 0.f);
  }
  __syncthreads();

  if (tid < 10) {
    float lg = -1e30f;
    if (tid < en - s) {
      float d = 0.f;
      for (int k = 0; k < 150; ++k) d += h2sh[tid][k] * w_out[k];
      lg = d;
    }
    att[tid] = lg;
  }
  if (tid >= 64 && tid < 66) {
    int r = tid - 64;
    int fi = (r == 0) ? f0 : f1;
    float nsq = 0.f;
    for (int k = 0; k < 50; ++k) {
      float v = feat_table[fi * 50 + k];
      nsq += v * v;
    }
    float n = sqrtf(nsq);
    scl[r] = fminf(1.f, 1.f / fmaxf(n, 1e-7f));
  }
  __syncthreads();

  if (tid == 0) {
    float m = -1e30f;
    for (int p = 0; p < 10; ++p) m = fmaxf(m, att[p]);
    float ex[10];
    float ssum = 0.f;
    for (int p = 0; p < 10; ++p) {
      ex[p] = expf(att[p] - m);
      ssum += ex[p];
    }
    for (int p = 0; p < 10; ++p) att[p] = ex[p] / ssum;
  }
  __syncthreads();

  if (tid < 300) {
    int d = tid;
    float xf = keys[s * 300 + d];
    float xl = keys[(en - 1) * 300 + d];
    float xh = 0.f;
#pragma unroll
    for (int p = 0; p < 10; ++p) {
      int row = clampi(s + p, 0, 1023);
      xh += att[p] * lstm_in[row * 450 + d];
    }
    enc[e * 1000 + d] = xf;
    enc[e * 1000 + 300 + d] = xl;
    enc[e * 1000 + 600 + d] = xh;
  }
  if (tid < 100) {
    int r = tid / 50, cc = tid % 50;
    int fi = (r == 0) ? f0 : f1;
    enc[e * 1000 + 900 + tid] = feat_table[fi * 50 + cc] * scl[r];
  }
}

// ---------------------------------------------------------------------------
// Kernel E: small = enc @ affine_W + affine_b   (4 spans per block)
// ---------------------------------------------------------------------------
__global__ __launch_bounds__(320) void k_affine(
    const float* __restrict__ enc, const float* __restrict__ W,
    const float* __restrict__ bias, float* __restrict__ small) {
  const int e0 = blockIdx.x * 4;
  const int tid = threadIdx.x;
  __shared__ float es[4][1000];
  for (int i = tid; i < 4000; i += 320) es[i / 1000][i % 1000] = enc[e0 * 1000 + i];
  __syncthreads();
  if (tid < 300) {
    float a0 = bias[tid], a1 = bias[tid], a2 = bias[tid], a3 = bias[tid];
    for (int k = 0; k < 1000; k += 4) {
      float w0 = W[(k + 0) * 300 + tid];
      float w1 = W[(k + 1) * 300 + tid];
      float w2 = W[(k + 2) * 300 + tid];
      float w3 = W[(k + 3) * 300 + tid];
      const float4 v0 = *(const float4*)(&es[0][k]);
      const float4 v1 = *(const float4*)(&es[1][k]);
      const float4 v2 = *(const float4*)(&es[2][k]);
      const float4 v3 = *(const float4*)(&es[3][k]);
      a0 += v0.x * w0 + v0.y * w1 + v0.z * w2 + v0.w * w3;
      a1 += v1.x * w0 + v1.y * w1 + v1.z * w2 + v1.w * w3;
      a2 += v2.x * w0 + v2.y * w1 + v2.z * w2 + v2.w * w3;
      a3 += v3.x * w0 + v3.y * w1 + v3.z * w2 + v3.w * w3;
    }
    small[(e0 + 0) * 300 + tid] = a0;
    small[(e0 + 1) * 300 + tid] = a1;
    small[(e0 + 2) * 300 + tid] = a2;
    small[(e0 + 3) * 300 + tid] = a3;
  }
}

// ---------------------------------------------------------------------------
__global__ __launch_bounds__(64) void k_renorm(
    const float* __restrict__ actors, float* __restrict__ actorsN) {
  const int a = blockIdx.x;
  const int l = threadIdx.x;
  float nsq = 0.f;
  for (int d = l; d < 300; d += 64) {
    float v = actors[a * 300 + d];
    nsq += v * v;
  }
  for (int off = 32; off; off >>= 1) nsq += __shfl_down(nsq, off);
  nsq = __shfl(nsq, 0);
  float sc = fminf(1.f, 1.f / fmaxf(sqrtf(nsq), 1e-7f));
  for (int d = l; d < 300; d += 64) actorsN[a * 300 + d] = actors[a * 300 + d] * sc;
}

// ---------------------------------------------------------------------------
__global__ __launch_bounds__(64) void k_lse(
    const float* __restrict__ link, float* __restrict__ out) {
  const int a = blockIdx.x;
  const int l = threadIdx.x;
  float v[8];
  float m = -1e30f;
#pragma unroll
  for (int i = 0; i < 8; ++i) {
    v[i] = link[a * 512 + l + i * 64];
    m = fmaxf(m, v[i]);
  }
  for (int off = 32; off; off >>= 1) m = fmaxf(m, __shfl_xor(m, off));
  float ssum = 0.f;
#pragma unroll
  for (int i = 0; i < 8; ++i) ssum += expf(v[i] - m);
  for (int off = 32; off; off >>= 1) ssum += __shfl_xor(ssum, off);
  if (l == 0) out[a] = logf(ssum) + m;
}

// ---------------------------------------------------------------------------
extern "C" void kernel_launch(void* const* d_in, const int* in_sizes, int n_in,
                              void* d_out, int out_size, void* d_ws, size_t ws_size,
                              hipStream_t stream) {
  const float* fast_text = (const float*)d_in[0];
  const float* actor_matrix = (const float*)d_in[1];
  const float* char_table = (const float*)d_in[2];
  const float* w3 = (const float*)d_in[3];
  const float* b3 = (const float*)d_in[4];
  const float* w4 = (const float*)d_in[5];
  const float* b4 = (const float*)d_in[6];
  const float* w5 = (const float*)d_in[7];
  const float* b5 = (const float*)d_in[8];
  const float* Wi_f = (const float*)d_in[9];
  const float* Wh_f = (const float*)d_in[10];
  const float* b_f = (const float*)d_in[11];
  const float* Wi_b = (const float*)d_in[12];
  const float* Wh_b = (const float*)d_in[13];
  const float* b_b = (const float*)d_in[14];
  const float* alpha_W1 = (const float*)d_in[15];
  const float* alpha_b1 = (const float*)d_in[16];
  const float* alpha_W2 = (const float*)d_in[17];
  const float* alpha_b2 = (const float*)d_in[18];
  const float* alpha_w_out = (const float*)d_in[19];
  const float* feat_table = (const float*)d_in[20];
  const float* affine_W = (const float*)d_in[21];
  const float* affine_b = (const float*)d_in[22];
  const int* word_ids = (const int*)d_in[23];
  const int* char_ids = (const int*)d_in[24];
  const int* espans = (const int*)d_in[25];

  float* ws = (float*)d_ws;
  float* lstm_in = ws;                 // 1024*450
  float* xpF = lstm_in + 460800;       // 1024*600
  float* xpB = xpF + 614400;           // 1024*600
  float* keys = xpB + 614400;          // 1024*300
  float* enc = keys + 307200;          // 512*1000
  float* small = enc + 512000;         // 512*300
  float* actN = small + 153600;        // 2000*300

  float* out = (float*)d_out;
  float* score_link = out + 2000;  // 2000 x 512

  k_token<<<1024, 64, 0, stream>>>(fast_text, char_table, w3, b3, w4, b4, w5, b5,
                                   word_ids, char_ids, lstm_in);
  gemm_xproj<<<dim3(16, 20), 256, 0, stream>>>(lstm_in, Wi_f, b_f, Wi_b, b_b,
                                               xpF, xpB);
  k_lstm<<<2, 640, 0, stream>>>(xpF, xpB, Wh_f, Wh_b, keys);
  k_renorm<<<2000, 64, 0, stream>>>(actor_matrix, actN);
  k_span<<<512, 320, 0, stream>>>(keys, lstm_in, alpha_W1, alpha_b1, alpha_W2,
                                  alpha_b2, alpha_w_out, feat_table, espans, enc);
  k_affine<<<128, 320, 0, stream>>>(enc, affine_W, affine_b, small);
  gemm_nt<<<dim3(32, 8), 256, 0, stream>>>(actN, small, nullptr, score_link,
                                           2000, 512, 300);
  k_lse<<<2000, 64, 0, stream>>>(score_link, out);
}